// Round 15
// baseline (111.940 us; speedup 1.0000x reference)
//
#include <hip/hip_runtime.h>

#define B_   8
#define HW   16384
#define CHW  (64*HW)
#define NPIX (8*16384)
#define EPS_ 1e-5f

typedef unsigned short u16;
typedef unsigned int   u32;
typedef unsigned long long u64;
typedef __attribute__((ext_vector_type(8))) short bf16x8;
typedef __attribute__((ext_vector_type(4))) float f32x4;

__device__ __forceinline__ float sgnf(float v){ return (float)((v>0.f)-(v<0.f)); }
__device__ __forceinline__ float bf2f(u16 h){ return __uint_as_float(((u32)h)<<16); }
__device__ __forceinline__ u16 f2bf(float f){
    u32 u = __float_as_uint(f);
    u += 0x7fffu + ((u>>16)&1u);
    return (u16)(u>>16);
}
__device__ __forceinline__ u32 pack2(float a, float b){
    return (u32)f2bf(a) | ((u32)f2bf(b)<<16);
}

// BN1 consts from exact integer popcount sums (8 banks). kA = sc1*A, etc.
__device__ __forceinline__ void bn1_consts(const u32* __restrict__ cnt,
                                           const float* __restrict__ AB,
                                           const float* __restrict__ g,
                                           const float* __restrict__ be,
                                           const float* __restrict__ pa,
                                           const float* __restrict__ mb,
                                           float* kA, float* kB,
                                           float* al, float* mbl, int tid){
    if (tid < 64){
        u32 spu = 0, squ = 0;
#pragma unroll
        for (int k = 0; k < 8; k++){
            spu += cnt[k*128 + tid];
            squ += cnt[k*128 + 64 + tid];
        }
        float A  = AB[tid], Bv = AB[64+tid];
        float sp = (float)spu, sq = (float)squ;
        float mpc = sp * (1.f/(float)NPIX);
        float e2  = sq * (1.f/(float)NPIX);
        float mean = fmaf(A, mpc, Bv);
        float var  = A*A*fmaxf(e2 - mpc*mpc, 0.f);
        float sc = g[tid] * rsqrtf(var + EPS_);
        float sh = be[tid] - mean*sc;
        kA[tid] = sc*A;
        kB[tid] = fmaf(sc, Bv, sh);
        al[tid] = pa[tid];
        mbl[tid]= mb[tid];
    }
}

// --------------------------------------------------------------- packb ----
// 64 pixels/block, 16 channels/wave: per-lane sign-bit packing (no ballots
// on x), u16 LDS transpose, exact integer BN1 sums to 8 atomic banks.
// Each block builds its own wbl via 16 ballots; block 0 additionally builds
// the global derived weights (wbg, AB, wqbf, M) lane-parallel.
__global__ __launch_bounds__(256) void packb(const float* __restrict__ x,
                                             const float* __restrict__ pre_w,
                                             const float* __restrict__ pre_bias,
                                             const float* __restrict__ post_w,
                                             const float* __restrict__ red_w,
                                             const float* __restrict__ span_w,
                                             u32* __restrict__ cnt,
                                             uint2* __restrict__ sb,
                                             u32* __restrict__ wbg,
                                             float* __restrict__ AB,
                                             u16* __restrict__ wqbf,
                                             float* __restrict__ M){
    __shared__ u32 wbl[128];
    __shared__ u16 sgn[64*4];        // [pixel][wave-group]
    __shared__ uint2 sbl[64];
    __shared__ u32 ps[256], qs[256];
    __shared__ float srl[32], ssl[9];
    __shared__ u32 rs[64], ssg[9];
    int tid  = threadIdx.x;
    int w    = tid >> 6, lane = tid & 63;

    // per-block: pre-weight sign rows via ballot (16 rows/wave)
#pragma unroll 4
    for (int rr = 0; rr < 16; rr++){
        int o = (w << 4) + rr;
        float pw = pre_w[o*64 + lane];
        u64 bal = __ballot((int)(__float_as_uint(pw) >> 31));
        if (lane == 0){ wbl[2*o] = (u32)bal; wbl[2*o+1] = (u32)(bal >> 32); }
    }

    int p0   = blockIdx.x * 64;
    int b    = p0 >> 14;
    int pix  = p0 & (HW-1);

    // 16 independent loads (channels w*16..w*16+15), then per-lane pack
    const float* xbase = x + (size_t)b*CHW + (size_t)(w*16)*HW + pix + lane;
    float v[16];
#pragma unroll
    for (int k = 0; k < 16; k++) v[k] = xbase[(size_t)k*HW];
    u32 bits = 0;
#pragma unroll
    for (int k = 0; k < 16; k++)
        bits |= (__float_as_uint(v[k]) >> 31) << k;
    sgn[lane*4 + w] = (u16)bits;
    __syncthreads();

    // assemble uint2 per pixel (little-endian u16 concat = transpose)
    if (tid < 64){
        uint2 q = *reinterpret_cast<const uint2*>(&sgn[tid*4]);
        sb[p0 + tid] = q;
        sbl[tid]     = q;
    }
    __syncthreads();

    // integer BN1 sums: thread (o, quad) covers 16 pixels
    int o  = tid & 63;
    int qd = tid >> 6;
    u32 w0 = wbl[2*o], w1 = wbl[2*o+1];
    u32 sp = 0, sq = 0;
#pragma unroll
    for (int i = 0; i < 16; i++){
        uint2 vv = sbl[qd*16 + i];
        u32 pc = (u32)(__popc(vv.x ^ w0) + __popc(vv.y ^ w1));
        sp += pc;
        sq += pc*pc;
    }
    ps[qd*64 + o] = sp;
    qs[qd*64 + o] = sq;
    __syncthreads();
    if (tid < 64){
        u32 S = ps[tid] + ps[64+tid] + ps[128+tid] + ps[192+tid];
        u32 Q = qs[tid] + qs[64+tid] + qs[128+tid] + qs[192+tid];
        u32* bank = cnt + (blockIdx.x & 7)*128;
        atomicAdd(&bank[tid],    S);
        atomicAdd(&bank[64+tid], Q);
    }

    // ---- block 0 only: build wbg/AB/wqbf/M (lane-parallel, once) ----
    if (blockIdx.x == 0){
#pragma unroll 2
        for (int rr = 0; rr < 16; rr++){
            int oo = (w << 4) + rr;
            float pw = pre_w[oo*64 + lane];
            float qw = post_w[oo*64 + lane];
            float t  = fabsf(pw);
            float t2 = fabsf(qw);
#pragma unroll
            for (int m = 1; m < 64; m <<= 1){
                t  += __shfl_xor(t,  m);
                t2 += __shfl_xor(t2, m);
            }
            float alpha = t * (1.f/64.f);
            float ct = alpha * sgnf(pw) * pre_bias[lane];
#pragma unroll
            for (int m = 1; m < 64; m <<= 1) ct += __shfl_xor(ct, m);
            u64 bal = __ballot((int)(__float_as_uint(pw) >> 31));
            if (lane == 0){
                wbg[2*oo]   = (u32)bal;
                wbg[2*oo+1] = (u32)(bal >> 32);
                AB[oo]      = -2.f * alpha;
                AB[64+oo]   = 64.f * alpha + ct;
            }
            wqbf[oo*64 + lane] = f2bf((t2 * (1.f/64.f)) * sgnf(qw));
        }
#pragma unroll 2
        for (int rr = 0; rr < 8; rr++){
            int r = (w << 3) + rr;
            float rw = red_w[r*64 + lane];
            float t = fabsf(rw);
#pragma unroll
            for (int m = 1; m < 64; m <<= 1) t += __shfl_xor(t, m);
            u64 bal = __ballot((int)(__float_as_uint(rw) >> 31));
            if (lane == 0){
                srl[r] = t * (1.f/64.f);
                rs[2*r] = (u32)bal; rs[2*r+1] = (u32)(bal >> 32);
            }
        }
        if (w < 3){
            for (int jj = 0; jj < 3; jj++){
                int j = w*3 + jj;
                float sw = (lane < 32) ? span_w[j*32 + lane] : 0.f;
                float t = fabsf(sw);
#pragma unroll
                for (int m = 1; m < 64; m <<= 1) t += __shfl_xor(t, m);
                u64 bal = __ballot((int)(lane < 32 ? (__float_as_uint(sw) >> 31) : 0u));
                if (lane == 0){ ssl[j] = t * (1.f/32.f); ssg[j] = (u32)bal; }
            }
        }
        __syncthreads();
        for (int e = tid; e < 576; e += 256){
            int i = e / 9, j = e - i*9;
            u32 sj = ssg[j];
            float m = 0.f;
#pragma unroll
            for (int r = 0; r < 32; r++){
                u32 br = (rs[2*r + (i >> 5)] >> (i & 31)) & 1u;
                u32 bs = (sj >> r) & 1u;
                float t = srl[r];
                m += (bs ^ br) ? -t : t;
            }
            M[e] = ssl[j] * m;
        }
    }
}

// ---------------------------------------------------------------- kerk ----
__global__ __launch_bounds__(256) void kerk(const uint2* __restrict__ sb,
                                            const u32* __restrict__ cnt,
                                            const float* __restrict__ AB,
                                            const u32* __restrict__ wb,
                                            const float* __restrict__ pre_g,
                                            const float* __restrict__ pre_b,
                                            const float* __restrict__ pa,
                                            const float* __restrict__ mb,
                                            const float* __restrict__ M,
                                            u16* __restrict__ ker){
    __shared__ float kA[64], kB[64], al[64], mbl[64];
    __shared__ u32 wbl[128];
    int tid = threadIdx.x;
    bn1_consts(cnt, AB, pre_g, pre_b, pa, mb, kA, kB, al, mbl, tid);
    if (tid < 128) wbl[tid] = wb[tid];
    __syncthreads();

    int p   = blockIdx.x*256 + tid;
    int b   = p >> 14;
    int pix = p & (HW-1);
    uint2 mv = sb[p];

    float acc[9];
#pragma unroll
    for (int j = 0; j < 9; j++) acc[j] = 0.f;
    for (int i = 0; i < 64; i++){
        u32 pc = (u32)(__popc(mv.x ^ wbl[2*i]) + __popc(mv.y ^ wbl[2*i+1]));
        float w = fmaf(kA[i], (float)pc, kB[i]);
        float z = fmaxf(w, 0.f) + al[i]*fminf(w, 0.f) + mbl[i];
#pragma unroll
        for (int j = 0; j < 9; j++)
            acc[j] = fmaf(M[i*9+j], z, acc[j]);
    }
    u16* kb = ker + (size_t)b*9*HW + pix;
#pragma unroll
    for (int j = 0; j < 9; j++) kb[(size_t)j*HW] = f2bf(acc[j]);
}

// ------------------------------------------------------------- gatherk ----
// Involution + BN2 partials (3-level shfl + LDS tree, deterministic).
__global__ __launch_bounds__(256) void gatherk(const uint2* __restrict__ sb,
                                               const u32* __restrict__ cnt,
                                               const float* __restrict__ AB,
                                               const u32* __restrict__ wb,
                                               const float* __restrict__ pre_g,
                                               const float* __restrict__ pre_b,
                                               const float* __restrict__ pa,
                                               const float* __restrict__ mb,
                                               const u16* __restrict__ ker,
                                               u16* __restrict__ y2,
                                               float2* __restrict__ part2){
    __shared__ float kA[64], kB[64], al[64], mbl[64];
    __shared__ u32 wbl[128];
    __shared__ uint2 sbT[768];       // 6 rows x 128 cols
    __shared__ float zr[8*6*132];    // 25.3KB
    __shared__ float2 sred[256];     // [wv][grp][cc] 2KB

    int tid = threadIdx.x;
    bn1_consts(cnt, AB, pre_g, pre_b, pa, mb, kA, kB, al, mbl, tid);
    if (tid < 128) wbl[tid] = wb[tid];
    if (tid < 96){
        int cc = tid / 12, rem = tid - cc*12, rr = rem >> 1, ed = rem & 1;
        zr[(cc*6 + rr)*132 + ed*129] = 0.f;
    }

    int bid = blockIdx.x;
    int b  = bid >> 8;
    int cg = (bid >> 5) & 7;
    int rg = bid & 31;
    int y0 = rg*4;
    int c0 = cg*8;

    const uint2* sbb = sb + (size_t)b*HW;
#pragma unroll
    for (int k = 0; k < 3; k++){
        int e  = tid + 256*k;
        int rr = e >> 7;
        int xx = e & 127;
        int gy = y0 + rr - 1;
        int gc = min(max(gy, 0), 127);
        sbT[e] = sbb[gc*128 + xx];
    }
    __syncthreads();

#pragma unroll
    for (int k = 0; k < 24; k++){
        int e  = tid + 256*k;
        int cc = e / 768;
        int r2 = e - cc*768;
        int rr = r2 >> 7;
        int xx = r2 & 127;
        int c  = c0 + cc;
        int gy = y0 + rr - 1;
        float z = 0.f;
        if ((unsigned)gy < 128u){
            uint2 v = sbT[rr*128 + xx];
            u32 pc = (u32)(__popc(v.x ^ wbl[2*c]) + __popc(v.y ^ wbl[2*c+1]));
            float w = fmaf(kA[c], (float)pc, kB[c]);
            z = fmaxf(w, 0.f) + al[c]*fminf(w, 0.f) + mbl[c];
        }
        zr[(cc*6 + rr)*132 + xx + 1] = z;
    }
    __syncthreads();

    {
        int lane2 = tid & 63;
        int wv    = tid >> 6;
        int x0    = lane2*2;
        int gp    = (y0 + wv)*128 + x0;

        float k0[9], k1[9];
        const u16* kb = ker + (size_t)b*9*HW + gp;
#pragma unroll
        for (int j = 0; j < 9; j++){
            u32 u = *reinterpret_cast<const u32*>(kb + (size_t)j*HW);
            k0[j] = __uint_as_float(u << 16);
            k1[j] = __uint_as_float(u & 0xffff0000u);
        }

        u32* yo = reinterpret_cast<u32*>(y2 + (size_t)(b*64 + c0)*HW + gp);
#pragma unroll
        for (int cc = 0; cc < 8; cc++){
            const float* zrow = &zr[(cc*6 + wv)*132 + x0];
            float o0 = 0.f, o1 = 0.f;
#pragma unroll
            for (int dy = 0; dy < 3; dy++){
                float2 za = *reinterpret_cast<const float2*>(zrow + dy*132);
                float2 zb = *reinterpret_cast<const float2*>(zrow + dy*132 + 2);
                o0 = fmaf(za.x, k0[dy*3+0], o0);
                o0 = fmaf(za.y, k0[dy*3+1], o0);
                o0 = fmaf(zb.x, k0[dy*3+2], o0);
                o1 = fmaf(za.y, k1[dy*3+0], o1);
                o1 = fmaf(zb.x, k1[dy*3+1], o1);
                o1 = fmaf(zb.y, k1[dy*3+2], o1);
            }
            yo[(size_t)cc*(HW/2)] = pack2(o0, o1);
            float sm = o0 + o1, qm = o0*o0 + o1*o1;
#pragma unroll
            for (int m = 1; m < 8; m <<= 1){
                sm += __shfl_xor(sm, m);
                qm += __shfl_xor(qm, m);
            }
            if ((lane2 & 7) == 0)
                sred[wv*64 + (lane2>>3)*8 + cc] = make_float2(sm, qm);
        }
    }
    __syncthreads();
    if (tid < 64){
        int cc = tid >> 3, gp2 = tid & 7;
        float S = 0.f, Q = 0.f;
#pragma unroll
        for (int wv = 0; wv < 4; wv++){
            float2 v = sred[wv*64 + gp2*8 + cc];
            S += v.x; Q += v.y;
        }
#pragma unroll
        for (int off = 4; off > 0; off >>= 1){
            S += __shfl_down(S, off);
            Q += __shfl_down(Q, off);
        }
        if (gp2 == 0)
            part2[(size_t)(c0 + cc)*256 + (b*32 + rg)] = make_float2(S, Q);
    }
}

// ----------------------------------------------------------- conv_post ----
// Inline combine2 (part2, L2-hot) + MFMA GEMM + BN3 partials.
__global__ __launch_bounds__(256) void conv_post(const u16* __restrict__ y2,
                                                 const float2* __restrict__ part2,
                                                 const float* __restrict__ mid_g,
                                                 const float* __restrict__ mid_b,
                                                 const float* __restrict__ pbias,
                                                 const u16* __restrict__ wqbf,
                                                 u16* __restrict__ y3,
                                                 float2* __restrict__ part3){
    __shared__ u16 sB[256*64];     // 32 KB (also scratch)
    __shared__ float scl[64], shl[64], pbl[64];

    int tid = threadIdx.x;

    // inline combine2
    {
        int c = tid & 63, q = tid >> 6;
        float S = 0.f, Q = 0.f;
        const float2* pc = part2 + (size_t)c*256 + q*64;
#pragma unroll 8
        for (int k = 0; k < 64; k++){
            float2 v = pc[k];
            S += v.x; Q += v.y;
        }
        float2* tmp = (float2*)sB;
        tmp[q*64 + c] = make_float2(S, Q);
        __syncthreads();
        if (tid < 64){
            float S2 = 0.f, Q2 = 0.f;
#pragma unroll
            for (int s = 0; s < 4; s++){
                float2 v = tmp[s*64 + tid];
                S2 += v.x; Q2 += v.y;
            }
            float mean = S2 * (1.f/(float)NPIX);
            float var  = fmaxf(Q2 * (1.f/(float)NPIX) - mean*mean, 0.f);
            float sc = mid_g[tid] * rsqrtf(var + EPS_);
            scl[tid] = sc;
            shl[tid] = mid_b[tid] - mean*sc;
            pbl[tid] = pbias[tid];
        }
    }
    __syncthreads();

    int b    = blockIdx.x >> 6;
    int pix0 = (blockIdx.x & 63) << 8;

    // stage B: relu(BN2(y2)) + post_bias, bf16, XOR-swizzled
    {
        int cp = tid & 31;
        int g  = tid >> 5;
        const u16* r0 = y2 + (size_t)(b*64 + 2*cp)*HW + pix0;
        const u16* r1 = r0 + HW;
        float s0 = scl[2*cp],   h0 = shl[2*cp],   p0 = pbl[2*cp];
        float s1 = scl[2*cp+1], h1 = shl[2*cp+1], p1 = pbl[2*cp+1];
#pragma unroll
        for (int it = 0; it < 4; it++){
            int oct = g + it*8;
            uint4 va = *reinterpret_cast<const uint4*>(r0 + oct*8);
            uint4 vb = *reinterpret_cast<const uint4*>(r1 + oct*8);
            u32 wa[4] = {va.x, va.y, va.z, va.w};
            u32 wc[4] = {vb.x, vb.y, vb.z, vb.w};
#pragma unroll
            for (int k = 0; k < 4; k++){
                int px = oct*8 + 2*k;
                float a0 = fmaf(s0, bf2f((u16)(wa[k] & 0xffffu)), h0);
                float a1 = fmaf(s0, bf2f((u16)(wa[k] >> 16)),     h0);
                float c0v= fmaf(s1, bf2f((u16)(wc[k] & 0xffffu)), h1);
                float c1v= fmaf(s1, bf2f((u16)(wc[k] >> 16)),     h1);
                a0 = fmaxf(a0, 0.f) + p0;  a1 = fmaxf(a1, 0.f) + p0;
                c0v= fmaxf(c0v,0.f) + p1;  c1v= fmaxf(c1v,0.f) + p1;
                int e0 = px*64     + ((2*cp) ^ ((px & 7) << 3));
                int e1 = (px+1)*64 + ((2*cp) ^ (((px+1) & 7) << 3));
                *reinterpret_cast<u32*>(&sB[e0]) = pack2(a0, c0v);
                *reinterpret_cast<u32*>(&sB[e1]) = pack2(a1, c1v);
            }
        }
    }

    int w  = tid >> 6;
    int l  = tid & 63;
    int lr = l & 15;
    int lk = l >> 4;

    bf16x8 af[4][2];
#pragma unroll
    for (int os = 0; os < 4; os++){
        int o = os*16 + lr;
#pragma unroll
        for (int kf = 0; kf < 2; kf++)
            af[os][kf] = *reinterpret_cast<const bf16x8*>(wqbf + o*64 + lk*8 + kf*32);
    }
    __syncthreads();

    f32x4 acc[4][4];
#pragma unroll
    for (int os = 0; os < 4; os++)
#pragma unroll
        for (int ns = 0; ns < 4; ns++)
            acc[os][ns] = (f32x4){0.f, 0.f, 0.f, 0.f};

#pragma unroll
    for (int ns = 0; ns < 4; ns++){
        int px  = w*64 + ns*16 + lr;
        int swz = (px & 7) << 3;
        bf16x8 b0 = *reinterpret_cast<const bf16x8*>(&sB[px*64 + ((lk*8)      ^ swz)]);
        bf16x8 b1 = *reinterpret_cast<const bf16x8*>(&sB[px*64 + ((lk*8 + 32) ^ swz)]);
#pragma unroll
        for (int os = 0; os < 4; os++){
            acc[os][ns] = __builtin_amdgcn_mfma_f32_16x16x32_bf16(af[os][0], b0, acc[os][ns], 0, 0, 0);
            acc[os][ns] = __builtin_amdgcn_mfma_f32_16x16x32_bf16(af[os][1], b1, acc[os][ns], 0, 0, 0);
        }
    }

    u16* yb = y3 + (size_t)(b*64)*HW + pix0;
#pragma unroll
    for (int os = 0; os < 4; os++){
#pragma unroll
        for (int ns = 0; ns < 4; ns++){
            int px = w*64 + ns*16 + lr;
#pragma unroll
            for (int r = 0; r < 4; r++){
                int o = os*16 + lk*4 + r;
                yb[(size_t)o*HW + px] = f2bf(acc[os][ns][r]);
            }
        }
    }

    __syncthreads();
    float2* wsum = (float2*)sB;
#pragma unroll
    for (int os = 0; os < 4; os++){
#pragma unroll
        for (int r = 0; r < 4; r++){
            float s = acc[os][0][r] + acc[os][1][r] + acc[os][2][r] + acc[os][3][r];
            float q = acc[os][0][r]*acc[os][0][r] + acc[os][1][r]*acc[os][1][r]
                    + acc[os][2][r]*acc[os][2][r] + acc[os][3][r]*acc[os][3][r];
#pragma unroll
            for (int m = 1; m < 16; m <<= 1){
                s += __shfl_xor(s, m);
                q += __shfl_xor(q, m);
            }
            if (lr == 0) wsum[w*64 + os*16 + lk*4 + r] = make_float2(s, q);
        }
    }
    __syncthreads();
    if (tid < 64){
        float S = 0.f, Q = 0.f;
#pragma unroll
        for (int ww = 0; ww < 4; ww++){
            float2 v = wsum[ww*64 + tid];
            S += v.x; Q += v.y;
        }
        part3[(size_t)tid*512 + blockIdx.x] = make_float2(S, Q);
    }
}

// --------------------------------------------------------------- final ----
// Inline combine3 (each block covers exactly one channel) + BN3 + residual.
__global__ __launch_bounds__(256) void finalk(const u16* __restrict__ y3,
                                              const float* __restrict__ x,
                                              const float2* __restrict__ part3,
                                              const float* __restrict__ gamma,
                                              const float* __restrict__ beta,
                                              float* __restrict__ out){
    __shared__ float2 wp[4];
    __shared__ float scsh_s[2];
    int tid = threadIdx.x;
    int c   = (blockIdx.x >> 2) & 63;       // block-uniform channel

    {
        const float2* pc = part3 + (size_t)c*512;
        float2 v0 = pc[tid], v1 = pc[tid+256];
        float S = v0.x + v1.x, Q = v0.y + v1.y;
        for (int off = 32; off > 0; off >>= 1){
            S += __shfl_down(S, off);
            Q += __shfl_down(Q, off);
        }
        if ((tid & 63) == 0) wp[tid>>6] = make_float2(S, Q);
        __syncthreads();
        if (tid == 0){
            float S2 = 0.f, Q2 = 0.f;
#pragma unroll
            for (int w = 0; w < 4; w++){ S2 += wp[w].x; Q2 += wp[w].y; }
            float mean = S2 * (1.f/(float)NPIX);
            float var  = fmaxf(Q2 * (1.f/(float)NPIX) - mean*mean, 0.f);
            float sc = gamma[c] * rsqrtf(var + EPS_);
            scsh_s[0] = sc;
            scsh_s[1] = beta[c] - mean*sc;
        }
    }
    __syncthreads();
    float s = scsh_s[0], t = scsh_s[1];

#pragma unroll
    for (int it = 0; it < 4; it++){
        int i4 = blockIdx.x*1024 + it*256 + tid;
        uint2  yv = reinterpret_cast<const uint2*>(y3)[i4];
        float4 bx = reinterpret_cast<const float4*>(x)[i4];
        float4 r;
        r.x = fmaf(s, __uint_as_float(yv.x << 16),          t) + bx.x;
        r.y = fmaf(s, __uint_as_float(yv.x & 0xffff0000u),  t) + bx.y;
        r.z = fmaf(s, __uint_as_float(yv.y << 16),          t) + bx.z;
        r.w = fmaf(s, __uint_as_float(yv.y & 0xffff0000u),  t) + bx.w;
        reinterpret_cast<float4*>(out)[i4] = r;
    }
}

// -------------------------------------------------------------- launch ----
extern "C" void kernel_launch(void* const* d_in, const int* in_sizes, int n_in,
                              void* d_out, int out_size, void* d_ws, size_t ws_size,
                              hipStream_t stream){
    const float* x        = (const float*)d_in[0];
    const float* pre_bias = (const float*)d_in[1];
    const float* pre_w    = (const float*)d_in[2];
    const float* pre_g    = (const float*)d_in[3];
    const float* pre_b    = (const float*)d_in[4];
    const float* pre_a    = (const float*)d_in[5];
    const float* mid_bias = (const float*)d_in[6];
    const float* red_w    = (const float*)d_in[7];
    const float* span_w   = (const float*)d_in[8];
    const float* mid_g    = (const float*)d_in[9];
    const float* mid_b    = (const float*)d_in[10];
    const float* post_bias= (const float*)d_in[12];
    const float* post_w   = (const float*)d_in[13];
    const float* post_g   = (const float*)d_in[14];
    const float* post_b   = (const float*)d_in[15];

    // workspace layout (float offsets); kerb spans [4456448, 5046272).
    float* ws    = (float*)d_ws;
    uint2* sb    = (uint2*)ws;                        // [0, 262144)
    u16*   y3b   = (u16*)(ws + 262144);               // [262144, 4456448)
    u16*   kerb  = (u16*)(ws + 4456448);              // [4456448, 5046272)
    u16*   wqbf  = (u16*)(ws + 5046272);              // [5046272, 5048320)
    float* M     = ws + 5048320;                      // [5048320, 5048960)
    u32*   wb    = (u32*)(ws + 5048960);              // [5048960, 5049088)
    float* AB    = ws + 5049088;                      // [5049088, 5049216)
    u32*   cnt   = (u32*)(ws + 5049216);              // [5049216, 5050240) 8 banks x 128
    float2* part2 = (float2*)(ws + 5050240);          // [5050240, 5083008)
    float2* part3 = (float2*)(ws + 5083008);          // [5083008, 5148544)

    u16*   y2b = (u16*)d_out;                         // scratch before finalk
    float* out = (float*)d_out;

    hipMemsetAsync(cnt, 0, 4096, stream);
    hipLaunchKernelGGL(packb, dim3(NPIX/64), dim3(256), 0, stream,
                       x, pre_w, pre_bias, post_w, red_w, span_w,
                       cnt, sb, wb, AB, wqbf, M);
    hipLaunchKernelGGL(kerk, dim3(NPIX/256), dim3(256), 0, stream,
                       sb, cnt, AB, wb, pre_g, pre_b, pre_a, mid_bias, M, kerb);
    hipLaunchKernelGGL(gatherk, dim3(2048), dim3(256), 0, stream,
                       sb, cnt, AB, wb, pre_g, pre_b, pre_a, mid_bias,
                       kerb, y2b, part2);
    hipLaunchKernelGGL(conv_post, dim3(512), dim3(256), 0, stream,
                       y2b, part2, mid_g, mid_b, post_bias, wqbf, y3b, part3);
    hipLaunchKernelGGL(finalk, dim3(2048), dim3(256), 0, stream,
                       y3b, x, part3, post_g, post_b, out);
}

// Round 16
// 96.714 us; speedup vs baseline: 1.1574x; 1.1574x over previous
//
#include <hip/hip_runtime.h>

#define B_   8
#define HW   16384
#define CHW  (64*HW)
#define NPIX (8*16384)
#define EPS_ 1e-5f

typedef unsigned short u16;
typedef unsigned int   u32;
typedef unsigned long long u64;
typedef __attribute__((ext_vector_type(8))) short bf16x8;
typedef __attribute__((ext_vector_type(4))) float f32x4;

__device__ __forceinline__ float sgnf(float v){ return (float)((v>0.f)-(v<0.f)); }
__device__ __forceinline__ float bf2f(u16 h){ return __uint_as_float(((u32)h)<<16); }
__device__ __forceinline__ u16 f2bf(float f){
    u32 u = __float_as_uint(f);
    u += 0x7fffu + ((u>>16)&1u);
    return (u16)(u>>16);
}
__device__ __forceinline__ u32 pack2(float a, float b){
    return (u32)f2bf(a) | ((u32)f2bf(b)<<16);
}

// BN1 consts from exact integer popcount sums (8 banks). kA = sc1*A, etc.
__device__ __forceinline__ void bn1_consts(const u32* __restrict__ cnt,
                                           const float* __restrict__ AB,
                                           const float* __restrict__ g,
                                           const float* __restrict__ be,
                                           const float* __restrict__ pa,
                                           const float* __restrict__ mb,
                                           float* kA, float* kB,
                                           float* al, float* mbl, int tid){
    if (tid < 64){
        u32 spu = 0, squ = 0;
#pragma unroll
        for (int k = 0; k < 8; k++){
            spu += cnt[k*128 + tid];
            squ += cnt[k*128 + 64 + tid];
        }
        float A  = AB[tid], Bv = AB[64+tid];
        float sp = (float)spu, sq = (float)squ;
        float mpc = sp * (1.f/(float)NPIX);
        float e2  = sq * (1.f/(float)NPIX);
        float mean = fmaf(A, mpc, Bv);
        float var  = A*A*fmaxf(e2 - mpc*mpc, 0.f);
        float sc = g[tid] * rsqrtf(var + EPS_);
        float sh = be[tid] - mean*sc;
        kA[tid] = sc*A;
        kB[tid] = fmaf(sc, Bv, sh);
        al[tid] = pa[tid];
        mbl[tid]= mb[tid];
    }
}

// ---------------------------------------------------------------- prep ----
// Lane-parallel weight build (r10 version, 576 threads); zeroes 1024 cnt.
__global__ __launch_bounds__(576) void prep(
                     const float* __restrict__ pre_w, const float* __restrict__ pre_bias,
                     const float* __restrict__ red_w, const float* __restrict__ span_w,
                     const float* __restrict__ post_w,
                     u32* __restrict__ wb, float* __restrict__ AB,
                     u16* __restrict__ wqbf, float* __restrict__ M,
                     u32* __restrict__ cnt){
    __shared__ float sr[32], ss[9];
    int t = threadIdx.x;
    for (int k = t; k < 1024; k += 576) cnt[k] = 0u;
    if (t < 64){
        float s = 0.f;
        for (int i = 0; i < 64; i++) s += fabsf(pre_w[t*64+i]);
        float alpha = s * (1.f/64.f);
        u32 b0 = 0, b1 = 0;
        for (int i = 0; i < 32; i++){
            b0 |= (__float_as_uint(pre_w[t*64+i])    >> 31) << i;
            b1 |= (__float_as_uint(pre_w[t*64+32+i]) >> 31) << i;
        }
        float c0 = 0.f;
        for (int i = 0; i < 64; i++)
            c0 += alpha * sgnf(pre_w[t*64+i]) * pre_bias[i];
        wb[2*t]   = b0;
        wb[2*t+1] = b1;
        AB[t]     = -2.f * alpha;
        AB[64+t]  = 64.f * alpha + c0;
    }
    if (t >= 64 && t < 128){
        int o = t - 64;
        float s2 = 0.f;
        for (int i = 0; i < 64; i++) s2 += fabsf(post_w[o*64+i]);
        s2 *= (1.f/64.f);
        for (int i = 0; i < 64; i++) wqbf[o*64+i] = f2bf(s2 * sgnf(post_w[o*64+i]));
    }
    if (t >= 128 && t < 160){
        int r = t - 128;
        float s = 0.f;
        for (int i = 0; i < 64; i++) s += fabsf(red_w[r*64+i]);
        sr[r] = s * (1.f/64.f);
    }
    if (t >= 160 && t < 169){
        int j = t - 160;
        float s = 0.f;
        for (int r = 0; r < 32; r++) s += fabsf(span_w[j*32+r]);
        ss[j] = s * (1.f/32.f);
    }
    __syncthreads();
    if (t < 576){
        int i = t / 9, j = t - (t/9)*9;
        float m = 0.f;
        for (int r = 0; r < 32; r++)
            m += sgnf(span_w[j*32+r]) * sr[r] * sgnf(red_w[r*64+i]);
        M[i*9+j] = ss[j] * m;
    }
}

// --------------------------------------------------------------- packb ----
// r14 version: 64 pixels/block, 16 channels/wave, per-lane sign packing,
// u16 LDS transpose, exact integer BN1 sums to 8 atomic banks.
__global__ __launch_bounds__(256) void packb(const float* __restrict__ x,
                                             const u32* __restrict__ wb,
                                             u32* __restrict__ cnt,
                                             uint2* __restrict__ sb){
    __shared__ u16 sgn[64*4];        // [pixel][wave-group]
    __shared__ uint2 sbl[64];
    __shared__ u32 ps[256], qs[256];
    int tid  = threadIdx.x;
    int w    = tid >> 6, lane = tid & 63;
    int p0   = blockIdx.x * 64;
    int b    = p0 >> 14;
    int pix  = p0 & (HW-1);

    // 16 independent loads (channels w*16..w*16+15), then per-lane pack
    const float* xbase = x + (size_t)b*CHW + (size_t)(w*16)*HW + pix + lane;
    float v[16];
#pragma unroll
    for (int k = 0; k < 16; k++) v[k] = xbase[(size_t)k*HW];
    u32 bits = 0;
#pragma unroll
    for (int k = 0; k < 16; k++)
        bits |= (__float_as_uint(v[k]) >> 31) << k;
    sgn[lane*4 + w] = (u16)bits;
    __syncthreads();

    // assemble uint2 per pixel (little-endian u16 concat = transpose)
    if (tid < 64){
        uint2 q = *reinterpret_cast<const uint2*>(&sgn[tid*4]);
        sb[p0 + tid] = q;
        sbl[tid]     = q;
    }
    __syncthreads();

    // integer BN1 sums: thread (o, quad) covers 16 pixels
    int o  = tid & 63;
    int qd = tid >> 6;
    u32 w0 = wb[2*o], w1 = wb[2*o+1];
    u32 sp = 0, sq = 0;
#pragma unroll
    for (int i = 0; i < 16; i++){
        uint2 vv = sbl[qd*16 + i];
        u32 pc = (u32)(__popc(vv.x ^ w0) + __popc(vv.y ^ w1));
        sp += pc;
        sq += pc*pc;
    }
    ps[qd*64 + o] = sp;
    qs[qd*64 + o] = sq;
    __syncthreads();
    if (tid < 64){
        u32 S = ps[tid] + ps[64+tid] + ps[128+tid] + ps[192+tid];
        u32 Q = qs[tid] + qs[64+tid] + qs[128+tid] + qs[192+tid];
        u32* bank = cnt + (blockIdx.x & 7)*128;
        atomicAdd(&bank[tid],    S);
        atomicAdd(&bank[64+tid], Q);
    }
}

// ---------------------------------------------------------------- kerk ----
__global__ __launch_bounds__(256) void kerk(const uint2* __restrict__ sb,
                                            const u32* __restrict__ cnt,
                                            const float* __restrict__ AB,
                                            const u32* __restrict__ wb,
                                            const float* __restrict__ pre_g,
                                            const float* __restrict__ pre_b,
                                            const float* __restrict__ pa,
                                            const float* __restrict__ mb,
                                            const float* __restrict__ M,
                                            u16* __restrict__ ker){
    __shared__ float kA[64], kB[64], al[64], mbl[64];
    __shared__ u32 wbl[128];
    int tid = threadIdx.x;
    bn1_consts(cnt, AB, pre_g, pre_b, pa, mb, kA, kB, al, mbl, tid);
    if (tid < 128) wbl[tid] = wb[tid];
    __syncthreads();

    int p   = blockIdx.x*256 + tid;
    int b   = p >> 14;
    int pix = p & (HW-1);
    uint2 mv = sb[p];

    float acc[9];
#pragma unroll
    for (int j = 0; j < 9; j++) acc[j] = 0.f;
    for (int i = 0; i < 64; i++){
        u32 pc = (u32)(__popc(mv.x ^ wbl[2*i]) + __popc(mv.y ^ wbl[2*i+1]));
        float w = fmaf(kA[i], (float)pc, kB[i]);
        float z = fmaxf(w, 0.f) + al[i]*fminf(w, 0.f) + mbl[i];
#pragma unroll
        for (int j = 0; j < 9; j++)
            acc[j] = fmaf(M[i*9+j], z, acc[j]);
    }
    u16* kb = ker + (size_t)b*9*HW + pix;
#pragma unroll
    for (int j = 0; j < 9; j++) kb[(size_t)j*HW] = f2bf(acc[j]);
}

// ------------------------------------------------------------- gatherk ----
// r10 version (6-level butterfly BN2 partials).
__global__ __launch_bounds__(256) void gatherk(const uint2* __restrict__ sb,
                                               const u32* __restrict__ cnt,
                                               const float* __restrict__ AB,
                                               const u32* __restrict__ wb,
                                               const float* __restrict__ pre_g,
                                               const float* __restrict__ pre_b,
                                               const float* __restrict__ pa,
                                               const float* __restrict__ mb,
                                               const u16* __restrict__ ker,
                                               u16* __restrict__ y2,
                                               float2* __restrict__ part2){
    __shared__ float kA[64], kB[64], al[64], mbl[64];
    __shared__ u32 wbl[128];
    __shared__ uint2 sbT[768];       // 6 rows x 128 cols
    __shared__ float zr[8*6*132];    // 25.3KB
    __shared__ float2 rowsum[32];

    int tid = threadIdx.x;
    bn1_consts(cnt, AB, pre_g, pre_b, pa, mb, kA, kB, al, mbl, tid);
    if (tid < 128) wbl[tid] = wb[tid];
    if (tid < 96){
        int cc = tid / 12, rem = tid - cc*12, rr = rem >> 1, ed = rem & 1;
        zr[(cc*6 + rr)*132 + ed*129] = 0.f;
    }

    int bid = blockIdx.x;
    int b  = bid >> 8;
    int cg = (bid >> 5) & 7;
    int rg = bid & 31;
    int y0 = rg*4;
    int c0 = cg*8;

    const uint2* sbb = sb + (size_t)b*HW;
#pragma unroll
    for (int k = 0; k < 3; k++){
        int e  = tid + 256*k;
        int rr = e >> 7;
        int xx = e & 127;
        int gy = y0 + rr - 1;
        int gc = min(max(gy, 0), 127);
        sbT[e] = sbb[gc*128 + xx];
    }
    __syncthreads();

#pragma unroll
    for (int k = 0; k < 24; k++){
        int e  = tid + 256*k;
        int cc = e / 768;
        int r2 = e - cc*768;
        int rr = r2 >> 7;
        int xx = r2 & 127;
        int c  = c0 + cc;
        int gy = y0 + rr - 1;
        float z = 0.f;
        if ((unsigned)gy < 128u){
            uint2 v = sbT[rr*128 + xx];
            u32 pc = (u32)(__popc(v.x ^ wbl[2*c]) + __popc(v.y ^ wbl[2*c+1]));
            float w = fmaf(kA[c], (float)pc, kB[c]);
            z = fmaxf(w, 0.f) + al[c]*fminf(w, 0.f) + mbl[c];
        }
        zr[(cc*6 + rr)*132 + xx + 1] = z;
    }
    __syncthreads();

    {
        int lane2 = tid & 63;
        int wv    = tid >> 6;
        int x0    = lane2*2;
        int gp    = (y0 + wv)*128 + x0;

        float k0[9], k1[9];
        const u16* kb = ker + (size_t)b*9*HW + gp;
#pragma unroll
        for (int j = 0; j < 9; j++){
            u32 u = *reinterpret_cast<const u32*>(kb + (size_t)j*HW);
            k0[j] = __uint_as_float(u << 16);
            k1[j] = __uint_as_float(u & 0xffff0000u);
        }

        u32* yo = reinterpret_cast<u32*>(y2 + (size_t)(b*64 + c0)*HW + gp);
#pragma unroll
        for (int cc = 0; cc < 8; cc++){
            const float* zrow = &zr[(cc*6 + wv)*132 + x0];
            float o0 = 0.f, o1 = 0.f;
#pragma unroll
            for (int dy = 0; dy < 3; dy++){
                float2 za = *reinterpret_cast<const float2*>(zrow + dy*132);
                float2 zb = *reinterpret_cast<const float2*>(zrow + dy*132 + 2);
                o0 = fmaf(za.x, k0[dy*3+0], o0);
                o0 = fmaf(za.y, k0[dy*3+1], o0);
                o0 = fmaf(zb.x, k0[dy*3+2], o0);
                o1 = fmaf(za.y, k1[dy*3+0], o1);
                o1 = fmaf(zb.x, k1[dy*3+1], o1);
                o1 = fmaf(zb.y, k1[dy*3+2], o1);
            }
            yo[(size_t)cc*(HW/2)] = pack2(o0, o1);
            float sm = o0 + o1, qm = o0*o0 + o1*o1;
#pragma unroll
            for (int m = 1; m < 64; m <<= 1){
                sm += __shfl_xor(sm, m);
                qm += __shfl_xor(qm, m);
            }
            if (lane2 == 0) rowsum[wv*8 + cc] = make_float2(sm, qm);
        }
    }
    __syncthreads();
    if (tid < 8){
        float S = 0.f, Q = 0.f;
#pragma unroll
        for (int w = 0; w < 4; w++){
            float2 v = rowsum[w*8 + tid];
            S += v.x; Q += v.y;
        }
        part2[(size_t)(c0 + tid)*256 + (b*32 + rg)] = make_float2(S, Q);
    }
}

// ------------------------------------------------------------- combinek ----
__global__ __launch_bounds__(256) void combinek(const float2* __restrict__ part,
                                                const float* __restrict__ gamma,
                                                const float* __restrict__ beta,
                                                float* __restrict__ scsh,
                                                int nsl){
    int c = blockIdx.x, tid = threadIdx.x;
    float S = 0.f, Q = 0.f;
    for (int k = tid; k < nsl; k += 256){
        float2 v = part[(size_t)c*nsl + k];
        S += v.x; Q += v.y;
    }
    for (int off = 32; off > 0; off >>= 1){
        S += __shfl_down(S, off);
        Q += __shfl_down(Q, off);
    }
    __shared__ float2 wp[4];
    if ((tid & 63) == 0) wp[tid>>6] = make_float2(S, Q);
    __syncthreads();
    if (tid == 0){
        float S2 = 0.f, Q2 = 0.f;
#pragma unroll
        for (int w = 0; w < 4; w++){ S2 += wp[w].x; Q2 += wp[w].y; }
        float mean = S2 * (1.f/(float)NPIX);
        float var  = fmaxf(Q2 * (1.f/(float)NPIX) - mean*mean, 0.f);
        float sc = gamma[c] * rsqrtf(var + EPS_);
        scsh[c]    = sc;
        scsh[64+c] = beta[c] - mean*sc;
    }
}

// ----------------------------------------------------------- conv_post ----
__global__ __launch_bounds__(256) void conv_post(const u16* __restrict__ y2,
                                                 const float* __restrict__ scsh_in,
                                                 const float* __restrict__ pbias,
                                                 const u16* __restrict__ wqbf,
                                                 u16* __restrict__ y3,
                                                 float2* __restrict__ part3){
    __shared__ u16 sB[256*64];     // 32 KB
    __shared__ float scl[64], shl[64], pbl[64];

    int tid = threadIdx.x;
    if (tid < 64){
        scl[tid] = scsh_in[tid];
        shl[tid] = scsh_in[64+tid];
        pbl[tid] = pbias[tid];
    }
    __syncthreads();

    int b    = blockIdx.x >> 6;
    int pix0 = (blockIdx.x & 63) << 8;

    {
        int cp = tid & 31;
        int g  = tid >> 5;
        const u16* r0 = y2 + (size_t)(b*64 + 2*cp)*HW + pix0;
        const u16* r1 = r0 + HW;
        float s0 = scl[2*cp],   h0 = shl[2*cp],   p0 = pbl[2*cp];
        float s1 = scl[2*cp+1], h1 = shl[2*cp+1], p1 = pbl[2*cp+1];
#pragma unroll
        for (int it = 0; it < 4; it++){
            int oct = g + it*8;
            uint4 va = *reinterpret_cast<const uint4*>(r0 + oct*8);
            uint4 vb = *reinterpret_cast<const uint4*>(r1 + oct*8);
            u32 wa[4] = {va.x, va.y, va.z, va.w};
            u32 wc[4] = {vb.x, vb.y, vb.z, vb.w};
#pragma unroll
            for (int k = 0; k < 4; k++){
                int px = oct*8 + 2*k;
                float a0 = fmaf(s0, bf2f((u16)(wa[k] & 0xffffu)), h0);
                float a1 = fmaf(s0, bf2f((u16)(wa[k] >> 16)),     h0);
                float c0v= fmaf(s1, bf2f((u16)(wc[k] & 0xffffu)), h1);
                float c1v= fmaf(s1, bf2f((u16)(wc[k] >> 16)),     h1);
                a0 = fmaxf(a0, 0.f) + p0;  a1 = fmaxf(a1, 0.f) + p0;
                c0v= fmaxf(c0v,0.f) + p1;  c1v= fmaxf(c1v,0.f) + p1;
                int e0 = px*64     + ((2*cp) ^ ((px & 7) << 3));
                int e1 = (px+1)*64 + ((2*cp) ^ (((px+1) & 7) << 3));
                *reinterpret_cast<u32*>(&sB[e0]) = pack2(a0, c0v);
                *reinterpret_cast<u32*>(&sB[e1]) = pack2(a1, c1v);
            }
        }
    }

    int w  = tid >> 6;
    int l  = tid & 63;
    int lr = l & 15;
    int lk = l >> 4;

    bf16x8 af[4][2];
#pragma unroll
    for (int os = 0; os < 4; os++){
        int o = os*16 + lr;
#pragma unroll
        for (int kf = 0; kf < 2; kf++)
            af[os][kf] = *reinterpret_cast<const bf16x8*>(wqbf + o*64 + lk*8 + kf*32);
    }
    __syncthreads();

    f32x4 acc[4][4];
#pragma unroll
    for (int os = 0; os < 4; os++)
#pragma unroll
        for (int ns = 0; ns < 4; ns++)
            acc[os][ns] = (f32x4){0.f, 0.f, 0.f, 0.f};

#pragma unroll
    for (int ns = 0; ns < 4; ns++){
        int px  = w*64 + ns*16 + lr;
        int swz = (px & 7) << 3;
        bf16x8 b0 = *reinterpret_cast<const bf16x8*>(&sB[px*64 + ((lk*8)      ^ swz)]);
        bf16x8 b1 = *reinterpret_cast<const bf16x8*>(&sB[px*64 + ((lk*8 + 32) ^ swz)]);
#pragma unroll
        for (int os = 0; os < 4; os++){
            acc[os][ns] = __builtin_amdgcn_mfma_f32_16x16x32_bf16(af[os][0], b0, acc[os][ns], 0, 0, 0);
            acc[os][ns] = __builtin_amdgcn_mfma_f32_16x16x32_bf16(af[os][1], b1, acc[os][ns], 0, 0, 0);
        }
    }

    u16* yb = y3 + (size_t)(b*64)*HW + pix0;
#pragma unroll
    for (int os = 0; os < 4; os++){
#pragma unroll
        for (int ns = 0; ns < 4; ns++){
            int px = w*64 + ns*16 + lr;
#pragma unroll
            for (int r = 0; r < 4; r++){
                int o = os*16 + lk*4 + r;
                yb[(size_t)o*HW + px] = f2bf(acc[os][ns][r]);
            }
        }
    }

    __syncthreads();
    float2* wsum = (float2*)sB;
#pragma unroll
    for (int os = 0; os < 4; os++){
#pragma unroll
        for (int r = 0; r < 4; r++){
            float s = acc[os][0][r] + acc[os][1][r] + acc[os][2][r] + acc[os][3][r];
            float q = acc[os][0][r]*acc[os][0][r] + acc[os][1][r]*acc[os][1][r]
                    + acc[os][2][r]*acc[os][2][r] + acc[os][3][r]*acc[os][3][r];
#pragma unroll
            for (int m = 1; m < 16; m <<= 1){
                s += __shfl_xor(s, m);
                q += __shfl_xor(q, m);
            }
            if (lr == 0) wsum[w*64 + os*16 + lk*4 + r] = make_float2(s, q);
        }
    }
    __syncthreads();
    if (tid < 64){
        float S = 0.f, Q = 0.f;
#pragma unroll
        for (int ww = 0; ww < 4; ww++){
            float2 v = wsum[ww*64 + tid];
            S += v.x; Q += v.y;
        }
        part3[(size_t)tid*512 + blockIdx.x] = make_float2(S, Q);
    }
}

// --------------------------------------------------------------- final ----
__global__ __launch_bounds__(256) void finalk(const u16* __restrict__ y3,
                                              const float* __restrict__ x,
                                              const float* __restrict__ scsh,
                                              float* __restrict__ out){
    __shared__ float scl[64], shl[64];
    int tid = threadIdx.x;
    if (tid < 64){ scl[tid] = scsh[tid]; shl[tid] = scsh[64+tid]; }
    __syncthreads();
#pragma unroll
    for (int it = 0; it < 4; it++){
        int i4 = blockIdx.x*1024 + it*256 + tid;
        int c  = (i4 >> 12) & 63;
        uint2  yv = reinterpret_cast<const uint2*>(y3)[i4];
        float4 bx = reinterpret_cast<const float4*>(x)[i4];
        float s = scl[c], t = shl[c];
        float4 r;
        r.x = fmaf(s, __uint_as_float(yv.x << 16),          t) + bx.x;
        r.y = fmaf(s, __uint_as_float(yv.x & 0xffff0000u),  t) + bx.y;
        r.z = fmaf(s, __uint_as_float(yv.y << 16),          t) + bx.z;
        r.w = fmaf(s, __uint_as_float(yv.y & 0xffff0000u),  t) + bx.w;
        reinterpret_cast<float4*>(out)[i4] = r;
    }
}

// -------------------------------------------------------------- launch ----
extern "C" void kernel_launch(void* const* d_in, const int* in_sizes, int n_in,
                              void* d_out, int out_size, void* d_ws, size_t ws_size,
                              hipStream_t stream){
    const float* x        = (const float*)d_in[0];
    const float* pre_bias = (const float*)d_in[1];
    const float* pre_w    = (const float*)d_in[2];
    const float* pre_g    = (const float*)d_in[3];
    const float* pre_b    = (const float*)d_in[4];
    const float* pre_a    = (const float*)d_in[5];
    const float* mid_bias = (const float*)d_in[6];
    const float* red_w    = (const float*)d_in[7];
    const float* span_w   = (const float*)d_in[8];
    const float* mid_g    = (const float*)d_in[9];
    const float* mid_b    = (const float*)d_in[10];
    const float* post_bias= (const float*)d_in[12];
    const float* post_w   = (const float*)d_in[13];
    const float* post_g   = (const float*)d_in[14];
    const float* post_b   = (const float*)d_in[15];

    // workspace layout (float offsets); kerb spans [4456448, 5046272).
    float* ws    = (float*)d_ws;
    uint2* sb    = (uint2*)ws;                        // [0, 262144)
    u16*   y3b   = (u16*)(ws + 262144);               // [262144, 4456448)
    u16*   kerb  = (u16*)(ws + 4456448);              // [4456448, 5046272)
    u16*   wqbf  = (u16*)(ws + 5046272);              // [5046272, 5048320)
    float* M     = ws + 5048320;                      // [5048320, 5048960)
    u32*   wb    = (u32*)(ws + 5048960);              // [5048960, 5049088)
    float* AB    = ws + 5049088;                      // [5049088, 5049216)
    u32*   cnt   = (u32*)(ws + 5049216);              // [5049216, 5050240) 8 banks x 128
    float2* part2 = (float2*)(ws + 5050240);          // [5050240, 5083008)
    float2* part3 = (float2*)(ws + 5083008);          // [5083008, 5148544)
    float* scsh2 = ws + 5148544;                      // [5148544, 5148672)
    float* scsh3 = ws + 5148672;                      // [5148672, 5148800)

    u16*   y2b = (u16*)d_out;                         // scratch before finalk
    float* out = (float*)d_out;

    hipLaunchKernelGGL(prep, dim3(1), dim3(576), 0, stream,
                       pre_w, pre_bias, red_w, span_w, post_w, wb, AB, wqbf, M, cnt);
    hipLaunchKernelGGL(packb, dim3(NPIX/64), dim3(256), 0, stream,
                       x, wb, cnt, sb);
    hipLaunchKernelGGL(kerk, dim3(NPIX/256), dim3(256), 0, stream,
                       sb, cnt, AB, wb, pre_g, pre_b, pre_a, mid_bias, M, kerb);
    hipLaunchKernelGGL(gatherk, dim3(2048), dim3(256), 0, stream,
                       sb, cnt, AB, wb, pre_g, pre_b, pre_a, mid_bias,
                       kerb, y2b, part2);
    hipLaunchKernelGGL(combinek, dim3(64), dim3(256), 0, stream,
                       part2, mid_g, mid_b, scsh2, 256);
    hipLaunchKernelGGL(conv_post, dim3(512), dim3(256), 0, stream,
                       y2b, scsh2, post_bias, wqbf, y3b, part3);
    hipLaunchKernelGGL(combinek, dim3(64), dim3(256), 0, stream,
                       part3, post_g, post_b, scsh3, 512);
    hipLaunchKernelGGL(finalk, dim3(2048), dim3(256), 0, stream,
                       y3b, x, part3 == nullptr ? scsh3 : scsh3, out);
}

// Round 17
// 92.698 us; speedup vs baseline: 1.2076x; 1.0433x over previous
//
#include <hip/hip_runtime.h>

#define B_   8
#define HW   16384
#define CHW  (64*HW)
#define NPIX (8*16384)
#define EPS_ 1e-5f

typedef unsigned short u16;
typedef unsigned int   u32;
typedef unsigned long long u64;
typedef __attribute__((ext_vector_type(8))) short bf16x8;
typedef __attribute__((ext_vector_type(4))) float f32x4;

__device__ __forceinline__ float sgnf(float v){ return (float)((v>0.f)-(v<0.f)); }
__device__ __forceinline__ float bf2f(u16 h){ return __uint_as_float(((u32)h)<<16); }
__device__ __forceinline__ u16 f2bf(float f){
    u32 u = __float_as_uint(f);
    u += 0x7fffu + ((u>>16)&1u);
    return (u16)(u>>16);
}
__device__ __forceinline__ u32 pack2(float a, float b){
    return (u32)f2bf(a) | ((u32)f2bf(b)<<16);
}

// BN1 consts from exact integer popcount sums (8 banks). kA = sc1*A, etc.
__device__ __forceinline__ void bn1_consts(const u32* __restrict__ cnt,
                                           const float* __restrict__ AB,
                                           const float* __restrict__ g,
                                           const float* __restrict__ be,
                                           const float* __restrict__ pa,
                                           const float* __restrict__ mb,
                                           float* kA, float* kB,
                                           float* al, float* mbl, int tid){
    if (tid < 64){
        u32 spu = 0, squ = 0;
#pragma unroll
        for (int k = 0; k < 8; k++){
            spu += cnt[k*128 + tid];
            squ += cnt[k*128 + 64 + tid];
        }
        float A  = AB[tid], Bv = AB[64+tid];
        float sp = (float)spu, sq = (float)squ;
        float mpc = sp * (1.f/(float)NPIX);
        float e2  = sq * (1.f/(float)NPIX);
        float mean = fmaf(A, mpc, Bv);
        float var  = A*A*fmaxf(e2 - mpc*mpc, 0.f);
        float sc = g[tid] * rsqrtf(var + EPS_);
        float sh = be[tid] - mean*sc;
        kA[tid] = sc*A;
        kB[tid] = fmaf(sc, Bv, sh);
        al[tid] = pa[tid];
        mbl[tid]= mb[tid];
    }
}

// ---------------------------------------------------------------- prep ----
__global__ __launch_bounds__(576) void prep(
                     const float* __restrict__ pre_w, const float* __restrict__ pre_bias,
                     const float* __restrict__ red_w, const float* __restrict__ span_w,
                     const float* __restrict__ post_w,
                     u32* __restrict__ wb, float* __restrict__ AB,
                     u16* __restrict__ wqbf, float* __restrict__ M,
                     u32* __restrict__ cnt){
    __shared__ float sr[32], ss[9];
    int t = threadIdx.x;
    for (int k = t; k < 1024; k += 576) cnt[k] = 0u;
    if (t < 64){
        float s = 0.f;
        for (int i = 0; i < 64; i++) s += fabsf(pre_w[t*64+i]);
        float alpha = s * (1.f/64.f);
        u32 b0 = 0, b1 = 0;
        for (int i = 0; i < 32; i++){
            b0 |= (__float_as_uint(pre_w[t*64+i])    >> 31) << i;
            b1 |= (__float_as_uint(pre_w[t*64+32+i]) >> 31) << i;
        }
        float c0 = 0.f;
        for (int i = 0; i < 64; i++)
            c0 += alpha * sgnf(pre_w[t*64+i]) * pre_bias[i];
        wb[2*t]   = b0;
        wb[2*t+1] = b1;
        AB[t]     = -2.f * alpha;
        AB[64+t]  = 64.f * alpha + c0;
    }
    if (t >= 64 && t < 128){
        int o = t - 64;
        float s2 = 0.f;
        for (int i = 0; i < 64; i++) s2 += fabsf(post_w[o*64+i]);
        s2 *= (1.f/64.f);
        for (int i = 0; i < 64; i++) wqbf[o*64+i] = f2bf(s2 * sgnf(post_w[o*64+i]));
    }
    if (t >= 128 && t < 160){
        int r = t - 128;
        float s = 0.f;
        for (int i = 0; i < 64; i++) s += fabsf(red_w[r*64+i]);
        sr[r] = s * (1.f/64.f);
    }
    if (t >= 160 && t < 169){
        int j = t - 160;
        float s = 0.f;
        for (int r = 0; r < 32; r++) s += fabsf(span_w[j*32+r]);
        ss[j] = s * (1.f/32.f);
    }
    __syncthreads();
    if (t < 576){
        int i = t / 9, j = t - (t/9)*9;
        float m = 0.f;
        for (int r = 0; r < 32; r++)
            m += sgnf(span_w[j*32+r]) * sr[r] * sgnf(red_w[r*64+i]);
        M[i*9+j] = ss[j] * m;
    }
}

// --------------------------------------------------------------- packb ----
__global__ __launch_bounds__(256) void packb(const float* __restrict__ x,
                                             const u32* __restrict__ wb,
                                             u32* __restrict__ cnt,
                                             uint2* __restrict__ sb){
    __shared__ u16 sgn[64*4];
    __shared__ uint2 sbl[64];
    __shared__ u32 ps[256], qs[256];
    int tid  = threadIdx.x;
    int w    = tid >> 6, lane = tid & 63;
    int p0   = blockIdx.x * 64;
    int b    = p0 >> 14;
    int pix  = p0 & (HW-1);

    const float* xbase = x + (size_t)b*CHW + (size_t)(w*16)*HW + pix + lane;
    float v[16];
#pragma unroll
    for (int k = 0; k < 16; k++) v[k] = xbase[(size_t)k*HW];
    u32 bits = 0;
#pragma unroll
    for (int k = 0; k < 16; k++)
        bits |= (__float_as_uint(v[k]) >> 31) << k;
    sgn[lane*4 + w] = (u16)bits;
    __syncthreads();

    if (tid < 64){
        uint2 q = *reinterpret_cast<const uint2*>(&sgn[tid*4]);
        sb[p0 + tid] = q;
        sbl[tid]     = q;
    }
    __syncthreads();

    int o  = tid & 63;
    int qd = tid >> 6;
    u32 w0 = wb[2*o], w1 = wb[2*o+1];
    u32 sp = 0, sq = 0;
#pragma unroll
    for (int i = 0; i < 16; i++){
        uint2 vv = sbl[qd*16 + i];
        u32 pc = (u32)(__popc(vv.x ^ w0) + __popc(vv.y ^ w1));
        sp += pc;
        sq += pc*pc;
    }
    ps[qd*64 + o] = sp;
    qs[qd*64 + o] = sq;
    __syncthreads();
    if (tid < 64){
        u32 S = ps[tid] + ps[64+tid] + ps[128+tid] + ps[192+tid];
        u32 Q = qs[tid] + qs[64+tid] + qs[128+tid] + qs[192+tid];
        u32* bank = cnt + (blockIdx.x & 7)*128;
        atomicAdd(&bank[tid],    S);
        atomicAdd(&bank[64+tid], Q);
    }
}

// ---------------------------------------------------------------- kerk ----
__global__ __launch_bounds__(256) void kerk(const uint2* __restrict__ sb,
                                            const u32* __restrict__ cnt,
                                            const float* __restrict__ AB,
                                            const u32* __restrict__ wb,
                                            const float* __restrict__ pre_g,
                                            const float* __restrict__ pre_b,
                                            const float* __restrict__ pa,
                                            const float* __restrict__ mb,
                                            const float* __restrict__ M,
                                            u16* __restrict__ ker){
    __shared__ float kA[64], kB[64], al[64], mbl[64];
    __shared__ u32 wbl[128];
    int tid = threadIdx.x;
    bn1_consts(cnt, AB, pre_g, pre_b, pa, mb, kA, kB, al, mbl, tid);
    if (tid < 128) wbl[tid] = wb[tid];
    __syncthreads();

    int p   = blockIdx.x*256 + tid;
    int b   = p >> 14;
    int pix = p & (HW-1);
    uint2 mv = sb[p];

    float acc[9];
#pragma unroll
    for (int j = 0; j < 9; j++) acc[j] = 0.f;
    for (int i = 0; i < 64; i++){
        u32 pc = (u32)(__popc(mv.x ^ wbl[2*i]) + __popc(mv.y ^ wbl[2*i+1]));
        float w = fmaf(kA[i], (float)pc, kB[i]);
        float z = fmaxf(w, 0.f) + al[i]*fminf(w, 0.f) + mbl[i];
#pragma unroll
        for (int j = 0; j < 9; j++)
            acc[j] = fmaf(M[i*9+j], z, acc[j]);
    }
    u16* kb = ker + (size_t)b*9*HW + pix;
#pragma unroll
    for (int j = 0; j < 9; j++) kb[(size_t)j*HW] = f2bf(acc[j]);
}

// ------------------------------------------------------------- gatherk ----
// Involution + BN2 partials via 3-level shfl + LDS tree (r14-validated).
__global__ __launch_bounds__(256) void gatherk(const uint2* __restrict__ sb,
                                               const u32* __restrict__ cnt,
                                               const float* __restrict__ AB,
                                               const u32* __restrict__ wb,
                                               const float* __restrict__ pre_g,
                                               const float* __restrict__ pre_b,
                                               const float* __restrict__ pa,
                                               const float* __restrict__ mb,
                                               const u16* __restrict__ ker,
                                               u16* __restrict__ y2,
                                               float2* __restrict__ part2){
    __shared__ float kA[64], kB[64], al[64], mbl[64];
    __shared__ u32 wbl[128];
    __shared__ uint2 sbT[768];       // 6 rows x 128 cols
    __shared__ float zr[8*6*132];    // 25.3KB
    __shared__ float2 sred[256];     // [wv][grp][cc] 2KB

    int tid = threadIdx.x;
    bn1_consts(cnt, AB, pre_g, pre_b, pa, mb, kA, kB, al, mbl, tid);
    if (tid < 128) wbl[tid] = wb[tid];
    if (tid < 96){
        int cc = tid / 12, rem = tid - cc*12, rr = rem >> 1, ed = rem & 1;
        zr[(cc*6 + rr)*132 + ed*129] = 0.f;
    }

    int bid = blockIdx.x;
    int b  = bid >> 8;
    int cg = (bid >> 5) & 7;
    int rg = bid & 31;
    int y0 = rg*4;
    int c0 = cg*8;

    const uint2* sbb = sb + (size_t)b*HW;
#pragma unroll
    for (int k = 0; k < 3; k++){
        int e  = tid + 256*k;
        int rr = e >> 7;
        int xx = e & 127;
        int gy = y0 + rr - 1;
        int gc = min(max(gy, 0), 127);
        sbT[e] = sbb[gc*128 + xx];
    }
    __syncthreads();

#pragma unroll
    for (int k = 0; k < 24; k++){
        int e  = tid + 256*k;
        int cc = e / 768;
        int r2 = e - cc*768;
        int rr = r2 >> 7;
        int xx = r2 & 127;
        int c  = c0 + cc;
        int gy = y0 + rr - 1;
        float z = 0.f;
        if ((unsigned)gy < 128u){
            uint2 v = sbT[rr*128 + xx];
            u32 pc = (u32)(__popc(v.x ^ wbl[2*c]) + __popc(v.y ^ wbl[2*c+1]));
            float w = fmaf(kA[c], (float)pc, kB[c]);
            z = fmaxf(w, 0.f) + al[c]*fminf(w, 0.f) + mbl[c];
        }
        zr[(cc*6 + rr)*132 + xx + 1] = z;
    }
    __syncthreads();

    {
        int lane2 = tid & 63;
        int wv    = tid >> 6;
        int x0    = lane2*2;
        int gp    = (y0 + wv)*128 + x0;

        float k0[9], k1[9];
        const u16* kb = ker + (size_t)b*9*HW + gp;
#pragma unroll
        for (int j = 0; j < 9; j++){
            u32 u = *reinterpret_cast<const u32*>(kb + (size_t)j*HW);
            k0[j] = __uint_as_float(u << 16);
            k1[j] = __uint_as_float(u & 0xffff0000u);
        }

        u32* yo = reinterpret_cast<u32*>(y2 + (size_t)(b*64 + c0)*HW + gp);
#pragma unroll
        for (int cc = 0; cc < 8; cc++){
            const float* zrow = &zr[(cc*6 + wv)*132 + x0];
            float o0 = 0.f, o1 = 0.f;
#pragma unroll
            for (int dy = 0; dy < 3; dy++){
                float2 za = *reinterpret_cast<const float2*>(zrow + dy*132);
                float2 zb = *reinterpret_cast<const float2*>(zrow + dy*132 + 2);
                o0 = fmaf(za.x, k0[dy*3+0], o0);
                o0 = fmaf(za.y, k0[dy*3+1], o0);
                o0 = fmaf(zb.x, k0[dy*3+2], o0);
                o1 = fmaf(za.y, k1[dy*3+0], o1);
                o1 = fmaf(zb.x, k1[dy*3+1], o1);
                o1 = fmaf(zb.y, k1[dy*3+2], o1);
            }
            yo[(size_t)cc*(HW/2)] = pack2(o0, o1);
            // 3-level butterfly -> per-8-lane-group partials (deterministic)
            float sm = o0 + o1, qm = o0*o0 + o1*o1;
#pragma unroll
            for (int m = 1; m < 8; m <<= 1){
                sm += __shfl_xor(sm, m);
                qm += __shfl_xor(qm, m);
            }
            if ((lane2 & 7) == 0)
                sred[wv*64 + (lane2>>3)*8 + cc] = make_float2(sm, qm);
        }
    }
    __syncthreads();
    if (tid < 64){
        int cc = tid >> 3, gp2 = tid & 7;
        float S = 0.f, Q = 0.f;
#pragma unroll
        for (int wv = 0; wv < 4; wv++){
            float2 v = sred[wv*64 + gp2*8 + cc];
            S += v.x; Q += v.y;
        }
#pragma unroll
        for (int off = 4; off > 0; off >>= 1){
            S += __shfl_down(S, off);
            Q += __shfl_down(Q, off);
        }
        if (gp2 == 0)
            part2[(size_t)(c0 + cc)*256 + (b*32 + rg)] = make_float2(S, Q);
    }
}

// ------------------------------------------------------------- combinek ----
__global__ __launch_bounds__(256) void combinek(const float2* __restrict__ part,
                                                const float* __restrict__ gamma,
                                                const float* __restrict__ beta,
                                                float* __restrict__ scsh,
                                                int nsl){
    int c = blockIdx.x, tid = threadIdx.x;
    float S = 0.f, Q = 0.f;
    for (int k = tid; k < nsl; k += 256){
        float2 v = part[(size_t)c*nsl + k];
        S += v.x; Q += v.y;
    }
    for (int off = 32; off > 0; off >>= 1){
        S += __shfl_down(S, off);
        Q += __shfl_down(Q, off);
    }
    __shared__ float2 wp[4];
    if ((tid & 63) == 0) wp[tid>>6] = make_float2(S, Q);
    __syncthreads();
    if (tid == 0){
        float S2 = 0.f, Q2 = 0.f;
#pragma unroll
        for (int w = 0; w < 4; w++){ S2 += wp[w].x; Q2 += wp[w].y; }
        float mean = S2 * (1.f/(float)NPIX);
        float var  = fmaxf(Q2 * (1.f/(float)NPIX) - mean*mean, 0.f);
        float sc = gamma[c] * rsqrtf(var + EPS_);
        scsh[c]    = sc;
        scsh[64+c] = beta[c] - mean*sc;
    }
}

// ----------------------------------------------------------- conv_post ----
__global__ __launch_bounds__(256) void conv_post(const u16* __restrict__ y2,
                                                 const float* __restrict__ scsh_in,
                                                 const float* __restrict__ pbias,
                                                 const u16* __restrict__ wqbf,
                                                 u16* __restrict__ y3,
                                                 float2* __restrict__ part3){
    __shared__ u16 sB[256*64];     // 32 KB
    __shared__ float scl[64], shl[64], pbl[64];

    int tid = threadIdx.x;
    if (tid < 64){
        scl[tid] = scsh_in[tid];
        shl[tid] = scsh_in[64+tid];
        pbl[tid] = pbias[tid];
    }
    __syncthreads();

    int b    = blockIdx.x >> 6;
    int pix0 = (blockIdx.x & 63) << 8;

    {
        int cp = tid & 31;
        int g  = tid >> 5;
        const u16* r0 = y2 + (size_t)(b*64 + 2*cp)*HW + pix0;
        const u16* r1 = r0 + HW;
        float s0 = scl[2*cp],   h0 = shl[2*cp],   p0 = pbl[2*cp];
        float s1 = scl[2*cp+1], h1 = shl[2*cp+1], p1 = pbl[2*cp+1];
#pragma unroll
        for (int it = 0; it < 4; it++){
            int oct = g + it*8;
            uint4 va = *reinterpret_cast<const uint4*>(r0 + oct*8);
            uint4 vb = *reinterpret_cast<const uint4*>(r1 + oct*8);
            u32 wa[4] = {va.x, va.y, va.z, va.w};
            u32 wc[4] = {vb.x, vb.y, vb.z, vb.w};
#pragma unroll
            for (int k = 0; k < 4; k++){
                int px = oct*8 + 2*k;
                float a0 = fmaf(s0, bf2f((u16)(wa[k] & 0xffffu)), h0);
                float a1 = fmaf(s0, bf2f((u16)(wa[k] >> 16)),     h0);
                float c0v= fmaf(s1, bf2f((u16)(wc[k] & 0xffffu)), h1);
                float c1v= fmaf(s1, bf2f((u16)(wc[k] >> 16)),     h1);
                a0 = fmaxf(a0, 0.f) + p0;  a1 = fmaxf(a1, 0.f) + p0;
                c0v= fmaxf(c0v,0.f) + p1;  c1v= fmaxf(c1v,0.f) + p1;
                int e0 = px*64     + ((2*cp) ^ ((px & 7) << 3));
                int e1 = (px+1)*64 + ((2*cp) ^ (((px+1) & 7) << 3));
                *reinterpret_cast<u32*>(&sB[e0]) = pack2(a0, c0v);
                *reinterpret_cast<u32*>(&sB[e1]) = pack2(a1, c1v);
            }
        }
    }

    int w  = tid >> 6;
    int l  = tid & 63;
    int lr = l & 15;
    int lk = l >> 4;

    bf16x8 af[4][2];
#pragma unroll
    for (int os = 0; os < 4; os++){
        int o = os*16 + lr;
#pragma unroll
        for (int kf = 0; kf < 2; kf++)
            af[os][kf] = *reinterpret_cast<const bf16x8*>(wqbf + o*64 + lk*8 + kf*32);
    }
    __syncthreads();

    f32x4 acc[4][4];
#pragma unroll
    for (int os = 0; os < 4; os++)
#pragma unroll
        for (int ns = 0; ns < 4; ns++)
            acc[os][ns] = (f32x4){0.f, 0.f, 0.f, 0.f};

#pragma unroll
    for (int ns = 0; ns < 4; ns++){
        int px  = w*64 + ns*16 + lr;
        int swz = (px & 7) << 3;
        bf16x8 b0 = *reinterpret_cast<const bf16x8*>(&sB[px*64 + ((lk*8)      ^ swz)]);
        bf16x8 b1 = *reinterpret_cast<const bf16x8*>(&sB[px*64 + ((lk*8 + 32) ^ swz)]);
#pragma unroll
        for (int os = 0; os < 4; os++){
            acc[os][ns] = __builtin_amdgcn_mfma_f32_16x16x32_bf16(af[os][0], b0, acc[os][ns], 0, 0, 0);
            acc[os][ns] = __builtin_amdgcn_mfma_f32_16x16x32_bf16(af[os][1], b1, acc[os][ns], 0, 0, 0);
        }
    }

    u16* yb = y3 + (size_t)(b*64)*HW + pix0;
#pragma unroll
    for (int os = 0; os < 4; os++){
#pragma unroll
        for (int ns = 0; ns < 4; ns++){
            int px = w*64 + ns*16 + lr;
#pragma unroll
            for (int r = 0; r < 4; r++){
                int o = os*16 + lk*4 + r;
                yb[(size_t)o*HW + px] = f2bf(acc[os][ns][r]);
            }
        }
    }

    __syncthreads();
    float2* wsum = (float2*)sB;
#pragma unroll
    for (int os = 0; os < 4; os++){
#pragma unroll
        for (int r = 0; r < 4; r++){
            float s = acc[os][0][r] + acc[os][1][r] + acc[os][2][r] + acc[os][3][r];
            float q = acc[os][0][r]*acc[os][0][r] + acc[os][1][r]*acc[os][1][r]
                    + acc[os][2][r]*acc[os][2][r] + acc[os][3][r]*acc[os][3][r];
#pragma unroll
            for (int m = 1; m < 16; m <<= 1){
                s += __shfl_xor(s, m);
                q += __shfl_xor(q, m);
            }
            if (lr == 0) wsum[w*64 + os*16 + lk*4 + r] = make_float2(s, q);
        }
    }
    __syncthreads();
    if (tid < 64){
        float S = 0.f, Q = 0.f;
#pragma unroll
        for (int ww = 0; ww < 4; ww++){
            float2 v = wsum[ww*64 + tid];
            S += v.x; Q += v.y;
        }
        part3[(size_t)tid*512 + blockIdx.x] = make_float2(S, Q);
    }
}

// --------------------------------------------------------------- final ----
__global__ __launch_bounds__(256) void finalk(const u16* __restrict__ y3,
                                              const float* __restrict__ x,
                                              const float* __restrict__ scsh,
                                              float* __restrict__ out){
    __shared__ float scl[64], shl[64];
    int tid = threadIdx.x;
    if (tid < 64){ scl[tid] = scsh[tid]; shl[tid] = scsh[64+tid]; }
    __syncthreads();
#pragma unroll
    for (int it = 0; it < 4; it++){
        int i4 = blockIdx.x*1024 + it*256 + tid;
        int c  = (i4 >> 12) & 63;
        uint2  yv = reinterpret_cast<const uint2*>(y3)[i4];
        float4 bx = reinterpret_cast<const float4*>(x)[i4];
        float s = scl[c], t = shl[c];
        float4 r;
        r.x = fmaf(s, __uint_as_float(yv.x << 16),          t) + bx.x;
        r.y = fmaf(s, __uint_as_float(yv.x & 0xffff0000u),  t) + bx.y;
        r.z = fmaf(s, __uint_as_float(yv.y << 16),          t) + bx.z;
        r.w = fmaf(s, __uint_as_float(yv.y & 0xffff0000u),  t) + bx.w;
        reinterpret_cast<float4*>(out)[i4] = r;
    }
}

// -------------------------------------------------------------- launch ----
extern "C" void kernel_launch(void* const* d_in, const int* in_sizes, int n_in,
                              void* d_out, int out_size, void* d_ws, size_t ws_size,
                              hipStream_t stream){
    const float* x        = (const float*)d_in[0];
    const float* pre_bias = (const float*)d_in[1];
    const float* pre_w    = (const float*)d_in[2];
    const float* pre_g    = (const float*)d_in[3];
    const float* pre_b    = (const float*)d_in[4];
    const float* pre_a    = (const float*)d_in[5];
    const float* mid_bias = (const float*)d_in[6];
    const float* red_w    = (const float*)d_in[7];
    const float* span_w   = (const float*)d_in[8];
    const float* mid_g    = (const float*)d_in[9];
    const float* mid_b    = (const float*)d_in[10];
    const float* post_bias= (const float*)d_in[12];
    const float* post_w   = (const float*)d_in[13];
    const float* post_g   = (const float*)d_in[14];
    const float* post_b   = (const float*)d_in[15];

    // workspace layout (float offsets); kerb spans [4456448, 5046272).
    float* ws    = (float*)d_ws;
    uint2* sb    = (uint2*)ws;                        // [0, 262144)
    u16*   y3b   = (u16*)(ws + 262144);               // [262144, 4456448)
    u16*   kerb  = (u16*)(ws + 4456448);              // [4456448, 5046272)
    u16*   wqbf  = (u16*)(ws + 5046272);              // [5046272, 5048320)
    float* M     = ws + 5048320;                      // [5048320, 5048960)
    u32*   wb    = (u32*)(ws + 5048960);              // [5048960, 5049088)
    float* AB    = ws + 5049088;                      // [5049088, 5049216)
    u32*   cnt   = (u32*)(ws + 5049216);              // [5049216, 5050240) 8 banks x 128
    float2* part2 = (float2*)(ws + 5050240);          // [5050240, 5083008)
    float2* part3 = (float2*)(ws + 5083008);          // [5083008, 5148544)
    float* scsh2 = ws + 5148544;                      // [5148544, 5148672)
    float* scsh3 = ws + 5148672;                      // [5148672, 5148800)

    u16*   y2b = (u16*)d_out;                         // scratch before finalk
    float* out = (float*)d_out;

    hipLaunchKernelGGL(prep, dim3(1), dim3(576), 0, stream,
                       pre_w, pre_bias, red_w, span_w, post_w, wb, AB, wqbf, M, cnt);
    hipLaunchKernelGGL(packb, dim3(NPIX/64), dim3(256), 0, stream,
                       x, wb, cnt, sb);
    hipLaunchKernelGGL(kerk, dim3(NPIX/256), dim3(256), 0, stream,
                       sb, cnt, AB, wb, pre_g, pre_b, pre_a, mid_bias, M, kerb);
    hipLaunchKernelGGL(gatherk, dim3(2048), dim3(256), 0, stream,
                       sb, cnt, AB, wb, pre_g, pre_b, pre_a, mid_bias,
                       kerb, y2b, part2);
    hipLaunchKernelGGL(combinek, dim3(64), dim3(256), 0, stream,
                       part2, mid_g, mid_b, scsh2, 256);
    hipLaunchKernelGGL(conv_post, dim3(512), dim3(256), 0, stream,
                       y2b, scsh2, post_bias, wqbf, y3b, part3);
    hipLaunchKernelGGL(combinek, dim3(64), dim3(256), 0, stream,
                       part3, post_g, post_b, scsh3, 512);
    hipLaunchKernelGGL(finalk, dim3(2048), dim3(256), 0, stream,
                       y3b, x, scsh3, out);
}

// Round 18
// 91.695 us; speedup vs baseline: 1.2208x; 1.0109x over previous
//
#include <hip/hip_runtime.h>

#define B_   8
#define HW   16384
#define CHW  (64*HW)
#define NPIX (8*16384)
#define EPS_ 1e-5f

typedef unsigned short u16;
typedef unsigned int   u32;
typedef unsigned long long u64;
typedef __attribute__((ext_vector_type(8))) short bf16x8;
typedef __attribute__((ext_vector_type(4))) float f32x4;

__device__ __forceinline__ float sgnf(float v){ return (float)((v>0.f)-(v<0.f)); }
__device__ __forceinline__ float bf2f(u16 h){ return __uint_as_float(((u32)h)<<16); }
__device__ __forceinline__ u16 f2bf(float f){
    u32 u = __float_as_uint(f);
    u += 0x7fffu + ((u>>16)&1u);
    return (u16)(u>>16);
}
__device__ __forceinline__ u32 pack2(float a, float b){
    return (u32)f2bf(a) | ((u32)f2bf(b)<<16);
}

// BN1 consts from exact integer popcount sums (8 banks). kA = sc1*A, etc.
__device__ __forceinline__ void bn1_consts(const u32* __restrict__ cnt,
                                           const float* __restrict__ AB,
                                           const float* __restrict__ g,
                                           const float* __restrict__ be,
                                           const float* __restrict__ pa,
                                           const float* __restrict__ mb,
                                           float* kA, float* kB,
                                           float* al, float* mbl, int tid){
    if (tid < 64){
        u32 spu = 0, squ = 0;
#pragma unroll
        for (int k = 0; k < 8; k++){
            spu += cnt[k*128 + tid];
            squ += cnt[k*128 + 64 + tid];
        }
        float A  = AB[tid], Bv = AB[64+tid];
        float sp = (float)spu, sq = (float)squ;
        float mpc = sp * (1.f/(float)NPIX);
        float e2  = sq * (1.f/(float)NPIX);
        float mean = fmaf(A, mpc, Bv);
        float var  = A*A*fmaxf(e2 - mpc*mpc, 0.f);
        float sc = g[tid] * rsqrtf(var + EPS_);
        float sh = be[tid] - mean*sc;
        kA[tid] = sc*A;
        kB[tid] = fmaf(sc, Bv, sh);
        al[tid] = pa[tid];
        mbl[tid]= mb[tid];
    }
}

// ---------------------------------------------------------------- prep ----
// ILP-4 partial sums + fused sign/c0 pass (loads pipelined, not serial).
__global__ __launch_bounds__(576) void prep(
                     const float* __restrict__ pre_w, const float* __restrict__ pre_bias,
                     const float* __restrict__ red_w, const float* __restrict__ span_w,
                     const float* __restrict__ post_w,
                     u32* __restrict__ wb, float* __restrict__ AB,
                     u16* __restrict__ wqbf, float* __restrict__ M,
                     u32* __restrict__ cnt){
    __shared__ float sr[32], ss[9];
    int t = threadIdx.x;
    for (int k = t; k < 1024; k += 576) cnt[k] = 0u;
    if (t < 64){
        const float* wr = pre_w + t*64;
        float s0=0.f, s1=0.f, s2=0.f, s3=0.f;
#pragma unroll
        for (int i = 0; i < 64; i += 4){
            s0 += fabsf(wr[i+0]);
            s1 += fabsf(wr[i+1]);
            s2 += fabsf(wr[i+2]);
            s3 += fabsf(wr[i+3]);
        }
        float alpha = ((s0+s1)+(s2+s3)) * (1.f/64.f);
        u32 b0 = 0, b1 = 0;
        float c0 = 0.f, c1 = 0.f;
#pragma unroll
        for (int i = 0; i < 32; i++){
            float wlo = wr[i], whi = wr[32+i];
            b0 |= (__float_as_uint(wlo) >> 31) << i;
            b1 |= (__float_as_uint(whi) >> 31) << i;
            c0 += sgnf(wlo) * pre_bias[i];
            c1 += sgnf(whi) * pre_bias[32+i];
        }
        wb[2*t]   = b0;
        wb[2*t+1] = b1;
        AB[t]     = -2.f * alpha;
        AB[64+t]  = 64.f * alpha + alpha*(c0 + c1);
    }
    if (t >= 64 && t < 128){
        int o = t - 64;
        const float* wr = post_w + o*64;
        float s0=0.f, s1=0.f, s2=0.f, s3=0.f;
#pragma unroll
        for (int i = 0; i < 64; i += 4){
            s0 += fabsf(wr[i+0]);
            s1 += fabsf(wr[i+1]);
            s2 += fabsf(wr[i+2]);
            s3 += fabsf(wr[i+3]);
        }
        float a = ((s0+s1)+(s2+s3)) * (1.f/64.f);
#pragma unroll
        for (int i = 0; i < 64; i++) wqbf[o*64+i] = f2bf(a * sgnf(wr[i]));
    }
    if (t >= 128 && t < 160){
        int r = t - 128;
        const float* wr = red_w + r*64;
        float s0=0.f, s1=0.f, s2=0.f, s3=0.f;
#pragma unroll
        for (int i = 0; i < 64; i += 4){
            s0 += fabsf(wr[i+0]);
            s1 += fabsf(wr[i+1]);
            s2 += fabsf(wr[i+2]);
            s3 += fabsf(wr[i+3]);
        }
        sr[r] = ((s0+s1)+(s2+s3)) * (1.f/64.f);
    }
    if (t >= 160 && t < 169){
        int j = t - 160;
        const float* wr = span_w + j*32;
        float s0=0.f, s1=0.f;
#pragma unroll
        for (int r = 0; r < 32; r += 2){
            s0 += fabsf(wr[r]);
            s1 += fabsf(wr[r+1]);
        }
        ss[j] = (s0+s1) * (1.f/32.f);
    }
    __syncthreads();
    if (t < 576){
        int i = t / 9, j = t - (t/9)*9;
        float m = 0.f;
#pragma unroll 8
        for (int r = 0; r < 32; r++)
            m += sgnf(span_w[j*32+r]) * sr[r] * sgnf(red_w[r*64+i]);
        M[i*9+j] = ss[j] * m;
    }
}

// --------------------------------------------------------------- packb ----
__global__ __launch_bounds__(256) void packb(const float* __restrict__ x,
                                             const u32* __restrict__ wb,
                                             u32* __restrict__ cnt,
                                             uint2* __restrict__ sb){
    __shared__ u16 sgn[64*4];
    __shared__ uint2 sbl[64];
    __shared__ u32 ps[256], qs[256];
    int tid  = threadIdx.x;
    int w    = tid >> 6, lane = tid & 63;
    int p0   = blockIdx.x * 64;
    int b    = p0 >> 14;
    int pix  = p0 & (HW-1);

    const float* xbase = x + (size_t)b*CHW + (size_t)(w*16)*HW + pix + lane;
    float v[16];
#pragma unroll
    for (int k = 0; k < 16; k++) v[k] = xbase[(size_t)k*HW];
    u32 bits = 0;
#pragma unroll
    for (int k = 0; k < 16; k++)
        bits |= (__float_as_uint(v[k]) >> 31) << k;
    sgn[lane*4 + w] = (u16)bits;
    __syncthreads();

    if (tid < 64){
        uint2 q = *reinterpret_cast<const uint2*>(&sgn[tid*4]);
        sb[p0 + tid] = q;
        sbl[tid]     = q;
    }
    __syncthreads();

    int o  = tid & 63;
    int qd = tid >> 6;
    u32 w0 = wb[2*o], w1 = wb[2*o+1];
    u32 sp = 0, sq = 0;
#pragma unroll
    for (int i = 0; i < 16; i++){
        uint2 vv = sbl[qd*16 + i];
        u32 pc = (u32)(__popc(vv.x ^ w0) + __popc(vv.y ^ w1));
        sp += pc;
        sq += pc*pc;
    }
    ps[qd*64 + o] = sp;
    qs[qd*64 + o] = sq;
    __syncthreads();
    if (tid < 64){
        u32 S = ps[tid] + ps[64+tid] + ps[128+tid] + ps[192+tid];
        u32 Q = qs[tid] + qs[64+tid] + qs[128+tid] + qs[192+tid];
        u32* bank = cnt + (blockIdx.x & 7)*128;
        atomicAdd(&bank[tid],    S);
        atomicAdd(&bank[64+tid], Q);
    }
}

// ---------------------------------------------------------------- kerk ----
__global__ __launch_bounds__(256) void kerk(const uint2* __restrict__ sb,
                                            const u32* __restrict__ cnt,
                                            const float* __restrict__ AB,
                                            const u32* __restrict__ wb,
                                            const float* __restrict__ pre_g,
                                            const float* __restrict__ pre_b,
                                            const float* __restrict__ pa,
                                            const float* __restrict__ mb,
                                            const float* __restrict__ M,
                                            u16* __restrict__ ker){
    __shared__ float kA[64], kB[64], al[64], mbl[64];
    __shared__ u32 wbl[128];
    int tid = threadIdx.x;
    bn1_consts(cnt, AB, pre_g, pre_b, pa, mb, kA, kB, al, mbl, tid);
    if (tid < 128) wbl[tid] = wb[tid];
    __syncthreads();

    int p   = blockIdx.x*256 + tid;
    int b   = p >> 14;
    int pix = p & (HW-1);
    uint2 mv = sb[p];

    float acc[9];
#pragma unroll
    for (int j = 0; j < 9; j++) acc[j] = 0.f;
    for (int i = 0; i < 64; i++){
        u32 pc = (u32)(__popc(mv.x ^ wbl[2*i]) + __popc(mv.y ^ wbl[2*i+1]));
        float w = fmaf(kA[i], (float)pc, kB[i]);
        float z = fmaxf(w, 0.f) + al[i]*fminf(w, 0.f) + mbl[i];
#pragma unroll
        for (int j = 0; j < 9; j++)
            acc[j] = fmaf(M[i*9+j], z, acc[j]);
    }
    u16* kb = ker + (size_t)b*9*HW + pix;
#pragma unroll
    for (int j = 0; j < 9; j++) kb[(size_t)j*HW] = f2bf(acc[j]);
}

// ------------------------------------------------------------- gatherk ----
// Involution + BN2 partials via 3-level shfl + LDS tree (deterministic).
__global__ __launch_bounds__(256) void gatherk(const uint2* __restrict__ sb,
                                               const u32* __restrict__ cnt,
                                               const float* __restrict__ AB,
                                               const u32* __restrict__ wb,
                                               const float* __restrict__ pre_g,
                                               const float* __restrict__ pre_b,
                                               const float* __restrict__ pa,
                                               const float* __restrict__ mb,
                                               const u16* __restrict__ ker,
                                               u16* __restrict__ y2,
                                               float2* __restrict__ part2){
    __shared__ float kA[64], kB[64], al[64], mbl[64];
    __shared__ u32 wbl[128];
    __shared__ uint2 sbT[768];       // 6 rows x 128 cols
    __shared__ float zr[8*6*132];    // 25.3KB
    __shared__ float2 sred[256];     // [wv][grp][cc] 2KB

    int tid = threadIdx.x;
    bn1_consts(cnt, AB, pre_g, pre_b, pa, mb, kA, kB, al, mbl, tid);
    if (tid < 128) wbl[tid] = wb[tid];
    if (tid < 96){
        int cc = tid / 12, rem = tid - cc*12, rr = rem >> 1, ed = rem & 1;
        zr[(cc*6 + rr)*132 + ed*129] = 0.f;
    }

    int bid = blockIdx.x;
    int b  = bid >> 8;
    int cg = (bid >> 5) & 7;
    int rg = bid & 31;
    int y0 = rg*4;
    int c0 = cg*8;

    const uint2* sbb = sb + (size_t)b*HW;
#pragma unroll
    for (int k = 0; k < 3; k++){
        int e  = tid + 256*k;
        int rr = e >> 7;
        int xx = e & 127;
        int gy = y0 + rr - 1;
        int gc = min(max(gy, 0), 127);
        sbT[e] = sbb[gc*128 + xx];
    }
    __syncthreads();

#pragma unroll
    for (int k = 0; k < 24; k++){
        int e  = tid + 256*k;
        int cc = e / 768;
        int r2 = e - cc*768;
        int rr = r2 >> 7;
        int xx = r2 & 127;
        int c  = c0 + cc;
        int gy = y0 + rr - 1;
        float z = 0.f;
        if ((unsigned)gy < 128u){
            uint2 v = sbT[rr*128 + xx];
            u32 pc = (u32)(__popc(v.x ^ wbl[2*c]) + __popc(v.y ^ wbl[2*c+1]));
            float w = fmaf(kA[c], (float)pc, kB[c]);
            z = fmaxf(w, 0.f) + al[c]*fminf(w, 0.f) + mbl[c];
        }
        zr[(cc*6 + rr)*132 + xx + 1] = z;
    }
    __syncthreads();

    {
        int lane2 = tid & 63;
        int wv    = tid >> 6;
        int x0    = lane2*2;
        int gp    = (y0 + wv)*128 + x0;

        float k0[9], k1[9];
        const u16* kb = ker + (size_t)b*9*HW + gp;
#pragma unroll
        for (int j = 0; j < 9; j++){
            u32 u = *reinterpret_cast<const u32*>(kb + (size_t)j*HW);
            k0[j] = __uint_as_float(u << 16);
            k1[j] = __uint_as_float(u & 0xffff0000u);
        }

        u32* yo = reinterpret_cast<u32*>(y2 + (size_t)(b*64 + c0)*HW + gp);
#pragma unroll
        for (int cc = 0; cc < 8; cc++){
            const float* zrow = &zr[(cc*6 + wv)*132 + x0];
            float o0 = 0.f, o1 = 0.f;
#pragma unroll
            for (int dy = 0; dy < 3; dy++){
                float2 za = *reinterpret_cast<const float2*>(zrow + dy*132);
                float2 zb = *reinterpret_cast<const float2*>(zrow + dy*132 + 2);
                o0 = fmaf(za.x, k0[dy*3+0], o0);
                o0 = fmaf(za.y, k0[dy*3+1], o0);
                o0 = fmaf(zb.x, k0[dy*3+2], o0);
                o1 = fmaf(za.y, k1[dy*3+0], o1);
                o1 = fmaf(zb.x, k1[dy*3+1], o1);
                o1 = fmaf(zb.y, k1[dy*3+2], o1);
            }
            yo[(size_t)cc*(HW/2)] = pack2(o0, o1);
            float sm = o0 + o1, qm = o0*o0 + o1*o1;
#pragma unroll
            for (int m = 1; m < 8; m <<= 1){
                sm += __shfl_xor(sm, m);
                qm += __shfl_xor(qm, m);
            }
            if ((lane2 & 7) == 0)
                sred[wv*64 + (lane2>>3)*8 + cc] = make_float2(sm, qm);
        }
    }
    __syncthreads();
    if (tid < 64){
        int cc = tid >> 3, gp2 = tid & 7;
        float S = 0.f, Q = 0.f;
#pragma unroll
        for (int wv = 0; wv < 4; wv++){
            float2 v = sred[wv*64 + gp2*8 + cc];
            S += v.x; Q += v.y;
        }
#pragma unroll
        for (int off = 4; off > 0; off >>= 1){
            S += __shfl_down(S, off);
            Q += __shfl_down(Q, off);
        }
        if (gp2 == 0)
            part2[(size_t)(c0 + cc)*256 + (b*32 + rg)] = make_float2(S, Q);
    }
}

// ------------------------------------------------------------- combinek ----
__global__ __launch_bounds__(256) void combinek(const float2* __restrict__ part,
                                                const float* __restrict__ gamma,
                                                const float* __restrict__ beta,
                                                float* __restrict__ scsh,
                                                int nsl){
    int c = blockIdx.x, tid = threadIdx.x;
    float S = 0.f, Q = 0.f;
    for (int k = tid; k < nsl; k += 256){
        float2 v = part[(size_t)c*nsl + k];
        S += v.x; Q += v.y;
    }
    for (int off = 32; off > 0; off >>= 1){
        S += __shfl_down(S, off);
        Q += __shfl_down(Q, off);
    }
    __shared__ float2 wp[4];
    if ((tid & 63) == 0) wp[tid>>6] = make_float2(S, Q);
    __syncthreads();
    if (tid == 0){
        float S2 = 0.f, Q2 = 0.f;
#pragma unroll
        for (int w = 0; w < 4; w++){ S2 += wp[w].x; Q2 += wp[w].y; }
        float mean = S2 * (1.f/(float)NPIX);
        float var  = fmaxf(Q2 * (1.f/(float)NPIX) - mean*mean, 0.f);
        float sc = gamma[c] * rsqrtf(var + EPS_);
        scsh[c]    = sc;
        scsh[64+c] = beta[c] - mean*sc;
    }
}

// ----------------------------------------------------------- conv_post ----
__global__ __launch_bounds__(256) void conv_post(const u16* __restrict__ y2,
                                                 const float* __restrict__ scsh_in,
                                                 const float* __restrict__ pbias,
                                                 const u16* __restrict__ wqbf,
                                                 u16* __restrict__ y3,
                                                 float2* __restrict__ part3){
    __shared__ u16 sB[256*64];     // 32 KB
    __shared__ float scl[64], shl[64], pbl[64];

    int tid = threadIdx.x;
    if (tid < 64){
        scl[tid] = scsh_in[tid];
        shl[tid] = scsh_in[64+tid];
        pbl[tid] = pbias[tid];
    }
    __syncthreads();

    int b    = blockIdx.x >> 6;
    int pix0 = (blockIdx.x & 63) << 8;

    {
        int cp = tid & 31;
        int g  = tid >> 5;
        const u16* r0 = y2 + (size_t)(b*64 + 2*cp)*HW + pix0;
        const u16* r1 = r0 + HW;
        float s0 = scl[2*cp],   h0 = shl[2*cp],   p0 = pbl[2*cp];
        float s1 = scl[2*cp+1], h1 = shl[2*cp+1], p1 = pbl[2*cp+1];
#pragma unroll
        for (int it = 0; it < 4; it++){
            int oct = g + it*8;
            uint4 va = *reinterpret_cast<const uint4*>(r0 + oct*8);
            uint4 vb = *reinterpret_cast<const uint4*>(r1 + oct*8);
            u32 wa[4] = {va.x, va.y, va.z, va.w};
            u32 wc[4] = {vb.x, vb.y, vb.z, vb.w};
#pragma unroll
            for (int k = 0; k < 4; k++){
                int px = oct*8 + 2*k;
                float a0 = fmaf(s0, bf2f((u16)(wa[k] & 0xffffu)), h0);
                float a1 = fmaf(s0, bf2f((u16)(wa[k] >> 16)),     h0);
                float c0v= fmaf(s1, bf2f((u16)(wc[k] & 0xffffu)), h1);
                float c1v= fmaf(s1, bf2f((u16)(wc[k] >> 16)),     h1);
                a0 = fmaxf(a0, 0.f) + p0;  a1 = fmaxf(a1, 0.f) + p0;
                c0v= fmaxf(c0v,0.f) + p1;  c1v= fmaxf(c1v,0.f) + p1;
                int e0 = px*64     + ((2*cp) ^ ((px & 7) << 3));
                int e1 = (px+1)*64 + ((2*cp) ^ (((px+1) & 7) << 3));
                *reinterpret_cast<u32*>(&sB[e0]) = pack2(a0, c0v);
                *reinterpret_cast<u32*>(&sB[e1]) = pack2(a1, c1v);
            }
        }
    }

    int w  = tid >> 6;
    int l  = tid & 63;
    int lr = l & 15;
    int lk = l >> 4;

    bf16x8 af[4][2];
#pragma unroll
    for (int os = 0; os < 4; os++){
        int o = os*16 + lr;
#pragma unroll
        for (int kf = 0; kf < 2; kf++)
            af[os][kf] = *reinterpret_cast<const bf16x8*>(wqbf + o*64 + lk*8 + kf*32);
    }
    __syncthreads();

    f32x4 acc[4][4];
#pragma unroll
    for (int os = 0; os < 4; os++)
#pragma unroll
        for (int ns = 0; ns < 4; ns++)
            acc[os][ns] = (f32x4){0.f, 0.f, 0.f, 0.f};

#pragma unroll
    for (int ns = 0; ns < 4; ns++){
        int px  = w*64 + ns*16 + lr;
        int swz = (px & 7) << 3;
        bf16x8 b0 = *reinterpret_cast<const bf16x8*>(&sB[px*64 + ((lk*8)      ^ swz)]);
        bf16x8 b1 = *reinterpret_cast<const bf16x8*>(&sB[px*64 + ((lk*8 + 32) ^ swz)]);
#pragma unroll
        for (int os = 0; os < 4; os++){
            acc[os][ns] = __builtin_amdgcn_mfma_f32_16x16x32_bf16(af[os][0], b0, acc[os][ns], 0, 0, 0);
            acc[os][ns] = __builtin_amdgcn_mfma_f32_16x16x32_bf16(af[os][1], b1, acc[os][ns], 0, 0, 0);
        }
    }

    u16* yb = y3 + (size_t)(b*64)*HW + pix0;
#pragma unroll
    for (int os = 0; os < 4; os++){
#pragma unroll
        for (int ns = 0; ns < 4; ns++){
            int px = w*64 + ns*16 + lr;
#pragma unroll
            for (int r = 0; r < 4; r++){
                int o = os*16 + lk*4 + r;
                yb[(size_t)o*HW + px] = f2bf(acc[os][ns][r]);
            }
        }
    }

    __syncthreads();
    float2* wsum = (float2*)sB;
#pragma unroll
    for (int os = 0; os < 4; os++){
#pragma unroll
        for (int r = 0; r < 4; r++){
            float s = acc[os][0][r] + acc[os][1][r] + acc[os][2][r] + acc[os][3][r];
            float q = acc[os][0][r]*acc[os][0][r] + acc[os][1][r]*acc[os][1][r]
                    + acc[os][2][r]*acc[os][2][r] + acc[os][3][r]*acc[os][3][r];
#pragma unroll
            for (int m = 1; m < 16; m <<= 1){
                s += __shfl_xor(s, m);
                q += __shfl_xor(q, m);
            }
            if (lr == 0) wsum[w*64 + os*16 + lk*4 + r] = make_float2(s, q);
        }
    }
    __syncthreads();
    if (tid < 64){
        float S = 0.f, Q = 0.f;
#pragma unroll
        for (int ww = 0; ww < 4; ww++){
            float2 v = wsum[ww*64 + tid];
            S += v.x; Q += v.y;
        }
        part3[(size_t)tid*512 + blockIdx.x] = make_float2(S, Q);
    }
}

// --------------------------------------------------------------- final ----
__global__ __launch_bounds__(256) void finalk(const u16* __restrict__ y3,
                                              const float* __restrict__ x,
                                              const float* __restrict__ scsh,
                                              float* __restrict__ out){
    __shared__ float scl[64], shl[64];
    int tid = threadIdx.x;
    if (tid < 64){ scl[tid] = scsh[tid]; shl[tid] = scsh[64+tid]; }
    __syncthreads();
#pragma unroll
    for (int it = 0; it < 4; it++){
        int i4 = blockIdx.x*1024 + it*256 + tid;
        int c  = (i4 >> 12) & 63;
        uint2  yv = reinterpret_cast<const uint2*>(y3)[i4];
        float4 bx = reinterpret_cast<const float4*>(x)[i4];
        float s = scl[c], t = shl[c];
        float4 r;
        r.x = fmaf(s, __uint_as_float(yv.x << 16),          t) + bx.x;
        r.y = fmaf(s, __uint_as_float(yv.x & 0xffff0000u),  t) + bx.y;
        r.z = fmaf(s, __uint_as_float(yv.y << 16),          t) + bx.z;
        r.w = fmaf(s, __uint_as_float(yv.y & 0xffff0000u),  t) + bx.w;
        reinterpret_cast<float4*>(out)[i4] = r;
    }
}

// -------------------------------------------------------------- launch ----
extern "C" void kernel_launch(void* const* d_in, const int* in_sizes, int n_in,
                              void* d_out, int out_size, void* d_ws, size_t ws_size,
                              hipStream_t stream){
    const float* x        = (const float*)d_in[0];
    const float* pre_bias = (const float*)d_in[1];
    const float* pre_w    = (const float*)d_in[2];
    const float* pre_g    = (const float*)d_in[3];
    const float* pre_b    = (const float*)d_in[4];
    const float* pre_a    = (const float*)d_in[5];
    const float* mid_bias = (const float*)d_in[6];
    const float* red_w    = (const float*)d_in[7];
    const float* span_w   = (const float*)d_in[8];
    const float* mid_g    = (const float*)d_in[9];
    const float* mid_b    = (const float*)d_in[10];
    const float* post_bias= (const float*)d_in[12];
    const float* post_w   = (const float*)d_in[13];
    const float* post_g   = (const float*)d_in[14];
    const float* post_b   = (const float*)d_in[15];

    // workspace layout (float offsets); kerb spans [4456448, 5046272).
    float* ws    = (float*)d_ws;
    uint2* sb    = (uint2*)ws;                        // [0, 262144)
    u16*   y3b   = (u16*)(ws + 262144);               // [262144, 4456448)
    u16*   kerb  = (u16*)(ws + 4456448);              // [4456448, 5046272)
    u16*   wqbf  = (u16*)(ws + 5046272);              // [5046272, 5048320)
    float* M     = ws + 5048320;                      // [5048320, 5048960)
    u32*   wb    = (u32*)(ws + 5048960);              // [5048960, 5049088)
    float* AB    = ws + 5049088;                      // [5049088, 5049216)
    u32*   cnt   = (u32*)(ws + 5049216);              // [5049216, 5050240) 8 banks x 128
    float2* part2 = (float2*)(ws + 5050240);          // [5050240, 5083008)
    float2* part3 = (float2*)(ws + 5083008);          // [5083008, 5148544)
    float* scsh2 = ws + 5148544;                      // [5148544, 5148672)
    float* scsh3 = ws + 5148672;                      // [5148672, 5148800)

    u16*   y2b = (u16*)d_out;                         // scratch before finalk
    float* out = (float*)d_out;

    hipLaunchKernelGGL(prep, dim3(1), dim3(576), 0, stream,
                       pre_w, pre_bias, red_w, span_w, post_w, wb, AB, wqbf, M, cnt);
    hipLaunchKernelGGL(packb, dim3(NPIX/64), dim3(256), 0, stream,
                       x, wb, cnt, sb);
    hipLaunchKernelGGL(kerk, dim3(NPIX/256), dim3(256), 0, stream,
                       sb, cnt, AB, wb, pre_g, pre_b, pre_a, mid_bias, M, kerb);
    hipLaunchKernelGGL(gatherk, dim3(2048), dim3(256), 0, stream,
                       sb, cnt, AB, wb, pre_g, pre_b, pre_a, mid_bias,
                       kerb, y2b, part2);
    hipLaunchKernelGGL(combinek, dim3(64), dim3(256), 0, stream,
                       part2, mid_g, mid_b, scsh2, 256);
    hipLaunchKernelGGL(conv_post, dim3(512), dim3(256), 0, stream,
                       y2b, scsh2, post_bias, wqbf, y3b, part3);
    hipLaunchKernelGGL(combinek, dim3(64), dim3(256), 0, stream,
                       part3, post_g, post_b, scsh3, 512);
    hipLaunchKernelGGL(finalk, dim3(2048), dim3(256), 0, stream,
                       y3b, x, scsh3, out);
}